// Round 4
// baseline (1895.792 us; speedup 1.0000x reference)
//
#include <hip/hip_runtime.h>
#include <cstdint>

#define B 16
#define TY 1600
#define TX 400
#define MAS 384
#define HID 768
#define NEGV -1e9f

typedef __bf16 bf16x8 __attribute__((ext_vector_type(8)));
typedef float  f32x4  __attribute__((ext_vector_type(4)));

__device__ __forceinline__ f32x4 mfma16(bf16x8 a, bf16x8 b, f32x4 c) {
  return __builtin_amdgcn_mfma_f32_16x16x32_bf16(a, b, c, 0, 0, 0);
}

// ---------------- fp32 -> bf16 hi/lo split with channel padding ----------------
__global__ void split_pad_k(const float* __restrict__ in, __bf16* __restrict__ oh,
                            __bf16* __restrict__ ol, int CIN, int CINP, long n) {
  long i = (long)blockIdx.x * 256 + threadIdx.x;
  if (i >= n) return;
  long row = i / CINP; int ci = (int)(i - row * CINP);
  float v = (ci < CIN) ? in[row * CIN + ci] : 0.f;
  __bf16 h = (__bf16)v;
  oh[i] = h; ol[i] = (__bf16)(v - (float)h);
}

// ---------------- weight repack+split: w[N][CIN][K] -> oh/ol[N][k*CINP + ci] ----------------
__global__ void wsplit_k(const float* __restrict__ w, __bf16* __restrict__ oh,
                         __bf16* __restrict__ ol, int CIN, int K_, int CINP, long n) {
  long i = (long)blockIdx.x * 256 + threadIdx.x;
  if (i >= n) return;
  long kdspan = (long)K_ * CINP;
  long nn = i / kdspan; int kd = (int)(i - nn * kdspan);
  int k = kd / CINP, ci = kd - k * CINP;
  float v = (ci < CIN) ? w[(nn * CIN + ci) * K_ + k] : 0.f;
  __bf16 h = (__bf16)v;
  oh[i] = h; ol[i] = (__bf16)(v - (float)h);
}

// ---------------- conv1 + ReGLU, split-bf16 MFMA ----------------
template<int CINP, int K, int T>
__global__ __launch_bounds__(256)
void conv1_mfma(const __bf16* __restrict__ xh, const __bf16* __restrict__ xl,
                const __bf16* __restrict__ wh, const __bf16* __restrict__ wl,
                const float* __restrict__ bias, const int* __restrict__ lens,
                __bf16* __restrict__ hh, __bf16* __restrict__ hl)
{
  constexpr int BM = 128, PAD = K / 2, ROWS = BM + K - 1, KD = K * CINP;
  __shared__ float4 xs[8 * ROWS];
  const int b = blockIdx.z, t0 = blockIdx.x * BM, n0 = blockIdx.y * 64;
  const int tid = threadIdx.x, wid = tid >> 6, lane = tid & 63;
  const int wm = wid >> 1, wn = wid & 1, lr = lane & 15, lg = lane >> 4;
  const int len = lens[b];
  const f32x4 Z4 = {0.f, 0.f, 0.f, 0.f};
  f32x4 acc_a[4][2], acc_g[4][2];
  #pragma unroll
  for (int m = 0; m < 4; ++m)
    #pragma unroll
    for (int n = 0; n < 2; ++n) { acc_a[m][n] = Z4; acc_g[m][n] = Z4; }

  #pragma unroll 1
  for (int ci0 = 0; ci0 < CINP; ci0 += 32) {
    __syncthreads();
    for (int e = tid; e < ROWS * 8; e += 256) {
      int row = e >> 3, sc = e & 7, spl = sc >> 2, cg = sc & 3;
      int t = t0 + row - PAD;
      float4 v = {0.f, 0.f, 0.f, 0.f};
      if (t >= 0 && t < len)
        v = *(const float4*)((spl ? xl : xh) + ((size_t)b * T + t) * CINP + ci0 + cg * 8);
      xs[(spl * 4 + cg) * ROWS + row] = v;
    }
    __syncthreads();
    #pragma unroll
    for (int k = 0; k < K; ++k) {
      bf16x8 ah[4], al[4];
      #pragma unroll
      for (int mf = 0; mf < 4; ++mf) {
        int row = wm * 64 + mf * 16 + lr + k;
        ah[mf] = *(const bf16x8*)&xs[lg * ROWS + row];
        al[mf] = *(const bf16x8*)&xs[(4 + lg) * ROWS + row];
      }
      size_t kd = (size_t)k * CINP + ci0 + lg * 8;
      #pragma unroll
      for (int nf = 0; nf < 2; ++nf) {
        int na = n0 + wn * 32 + nf * 16 + lr;
        bf16x8 bah = *(const bf16x8*)(wh + (size_t)na * KD + kd);
        bf16x8 bal = *(const bf16x8*)(wl + (size_t)na * KD + kd);
        bf16x8 bgh = *(const bf16x8*)(wh + (size_t)(na + HID) * KD + kd);
        bf16x8 bgl = *(const bf16x8*)(wl + (size_t)(na + HID) * KD + kd);
        #pragma unroll
        for (int mf = 0; mf < 4; ++mf) {
          acc_a[mf][nf] = mfma16(ah[mf], bah, acc_a[mf][nf]);
          acc_a[mf][nf] = mfma16(ah[mf], bal, acc_a[mf][nf]);
          acc_a[mf][nf] = mfma16(al[mf], bah, acc_a[mf][nf]);
          acc_g[mf][nf] = mfma16(ah[mf], bgh, acc_g[mf][nf]);
          acc_g[mf][nf] = mfma16(ah[mf], bgl, acc_g[mf][nf]);
          acc_g[mf][nf] = mfma16(al[mf], bgh, acc_g[mf][nf]);
        }
      }
    }
  }
  #pragma unroll
  for (int nf = 0; nf < 2; ++nf) {
    int c = n0 + wn * 32 + nf * 16 + lr;
    float ba = bias[c], bg = bias[c + HID];
    #pragma unroll
    for (int mf = 0; mf < 4; ++mf) {
      #pragma unroll
      for (int r = 0; r < 4; ++r) {
        int t = t0 + wm * 64 + mf * 16 + lg * 4 + r;
        if (t < T) {
          float a = acc_a[mf][nf][r] + ba;
          float g = acc_g[mf][nf][r] + bg;
          float v = a * fmaxf(g, 0.f);
          __bf16 vh = (__bf16)v;
          size_t o = ((size_t)b * T + t) * HID + c;
          hh[o] = vh;
          hl[o] = (__bf16)(v - (float)vh);
        }
      }
    }
  }
}

// ---------------- conv2 / linear, split-bf16 MFMA ----------------
template<int CINP, int K, int T, bool MASK, bool SPLITOUT, bool STORET>
__global__ __launch_bounds__(256)
void conv2_mfma(const __bf16* __restrict__ xh, const __bf16* __restrict__ xl,
                const __bf16* __restrict__ wh, const __bf16* __restrict__ wl,
                const float* __restrict__ bias, const int* __restrict__ lens,
                float* __restrict__ out, __bf16* __restrict__ oh, __bf16* __restrict__ ol)
{
  constexpr int BM = 128, PAD = K / 2, ROWS = BM + K - 1, KD = K * CINP;
  __shared__ float4 xs[8 * ROWS];
  const int b = blockIdx.z, t0 = blockIdx.x * BM, n0 = blockIdx.y * 128;
  const int tid = threadIdx.x, wid = tid >> 6, lane = tid & 63;
  const int wm = wid >> 1, wn = wid & 1, lr = lane & 15, lg = lane >> 4;
  const int len = lens[b];
  const f32x4 Z4 = {0.f, 0.f, 0.f, 0.f};
  f32x4 acc[4][4];
  #pragma unroll
  for (int m = 0; m < 4; ++m)
    #pragma unroll
    for (int n = 0; n < 4; ++n) acc[m][n] = Z4;

  #pragma unroll 1
  for (int ci0 = 0; ci0 < CINP; ci0 += 32) {
    __syncthreads();
    for (int e = tid; e < ROWS * 8; e += 256) {
      int row = e >> 3, sc = e & 7, spl = sc >> 2, cg = sc & 3;
      int t = t0 + row - PAD;
      float4 v = {0.f, 0.f, 0.f, 0.f};
      if (t >= 0 && t < len)
        v = *(const float4*)((spl ? xl : xh) + ((size_t)b * T + t) * CINP + ci0 + cg * 8);
      xs[(spl * 4 + cg) * ROWS + row] = v;
    }
    __syncthreads();
    #pragma unroll
    for (int k = 0; k < K; ++k) {
      bf16x8 ah[4], al[4];
      #pragma unroll
      for (int mf = 0; mf < 4; ++mf) {
        int row = wm * 64 + mf * 16 + lr + k;
        ah[mf] = *(const bf16x8*)&xs[lg * ROWS + row];
        al[mf] = *(const bf16x8*)&xs[(4 + lg) * ROWS + row];
      }
      size_t kd = (size_t)k * CINP + ci0 + lg * 8;
      #pragma unroll
      for (int nf = 0; nf < 4; ++nf) {
        int nc = n0 + wn * 64 + nf * 16 + lr;
        bf16x8 bh = *(const bf16x8*)(wh + (size_t)nc * KD + kd);
        bf16x8 bl = *(const bf16x8*)(wl + (size_t)nc * KD + kd);
        #pragma unroll
        for (int mf = 0; mf < 4; ++mf) {
          acc[mf][nf] = mfma16(ah[mf], bh, acc[mf][nf]);
          acc[mf][nf] = mfma16(ah[mf], bl, acc[mf][nf]);
          acc[mf][nf] = mfma16(al[mf], bh, acc[mf][nf]);
        }
      }
    }
  }
  #pragma unroll
  for (int nf = 0; nf < 4; ++nf) {
    int c = n0 + wn * 64 + nf * 16 + lr;
    float bb = bias[c];
    #pragma unroll
    for (int mf = 0; mf < 4; ++mf) {
      #pragma unroll
      for (int r = 0; r < 4; ++r) {
        int t = t0 + wm * 64 + mf * 16 + lg * 4 + r;
        if (t < T) {
          float v = acc[mf][nf][r] + bb;
          if (MASK && t >= len) v = 0.f;
          if (SPLITOUT) {
            __bf16 vh = (__bf16)v;
            size_t o = ((size_t)b * T + t) * MAS + c;
            oh[o] = vh;
            ol[o] = (__bf16)(v - (float)vh);
          } else if (STORET) {
            out[((size_t)b * MAS + c) * T + t] = v;
          } else {
            out[((size_t)b * T + t) * MAS + c] = v;
          }
        }
      }
    }
  }
}

// ---------------- scores + softmax + safe_log ----------------
__global__ __launch_bounds__(512)
void scores_k(const float* __restrict__ q, const float* __restrict__ kT,
              const int* __restrict__ xl, const int* __restrict__ yl,
              float* __restrict__ oattn, float* __restrict__ ologp)
{
  __shared__ float qs[16 * 384];
  __shared__ float tmp[8];
  const int b = blockIdx.y, y0 = blockIdx.x * 16, tid = threadIdx.x;
  for (int e = tid; e < 16 * 384; e += 512)
    qs[e] = q[((size_t)b * TY + (y0 + e / 384)) * 384 + (e - (e / 384) * 384)];
  __syncthreads();
  float acc[16];
  #pragma unroll
  for (int i = 0; i < 16; ++i) acc[i] = 0.f;
  const int x = tid;
  if (x < TX) {
    const float* kb = kT + (size_t)b * MAS * TX + x;
    for (int d = 0; d < 384; d += 4) {
      float k0 = kb[(size_t)(d + 0) * TX], k1 = kb[(size_t)(d + 1) * TX];
      float k2 = kb[(size_t)(d + 2) * TX], k3 = kb[(size_t)(d + 3) * TX];
      #pragma unroll
      for (int yy = 0; yy < 16; ++yy) {
        float4 qv = *(const float4*)&qs[yy * 384 + d];
        acc[yy] = fmaf(qv.x, k0, fmaf(qv.y, k1, fmaf(qv.z, k2, fmaf(qv.w, k3, acc[yy]))));
      }
    }
  }
  const int xlen = xl[b], ylen = yl[b];
  const float scale = 0.05103103630798288f;
  const bool xpad = (x >= xlen);
  const int wv = tid >> 6, ln = tid & 63;
  #pragma unroll 1
  for (int yy = 0; yy < 16; ++yy) {
    int y = y0 + yy;
    float s = -3.0e38f;
    if (x < TX) {
      s = acc[yy] * scale;
      if (xpad && (y >= ylen)) s = -1e-9f;
    }
    float m = s;
    for (int off = 32; off; off >>= 1) m = fmaxf(m, __shfl_xor(m, off));
    if (ln == 0) tmp[wv] = m;
    __syncthreads();
    float mx = fmaxf(fmaxf(fmaxf(tmp[0], tmp[1]), fmaxf(tmp[2], tmp[3])),
                     fmaxf(fmaxf(tmp[4], tmp[5]), fmaxf(tmp[6], tmp[7])));
    __syncthreads();
    float e = (x < TX) ? expf(s - mx) : 0.f;
    float sm = e;
    for (int off = 32; off; off >>= 1) sm += __shfl_xor(sm, off);
    if (ln == 0) tmp[wv] = sm;
    __syncthreads();
    float tot = tmp[0] + tmp[1] + tmp[2] + tmp[3] + tmp[4] + tmp[5] + tmp[6] + tmp[7];
    __syncthreads();
    if (x < TX) {
      float w = e / tot;
      size_t o = ((size_t)b * TY + y) * TX + x;
      oattn[o] = w;
      ologp[o] = logf(w + 1e-6f);
    }
  }
}

// ---------------- MAS: deep-pipelined forward DP + chunked wave-parallel backtrack ----------------
// lane l owns x in [8l, 8l+8); bits[b][y][byte=x>>3] bit (x&7) = (v[y-1][x-1] > v[y-1][x])
__global__ __launch_bounds__(64)
void mas_k(const float* __restrict__ logprob, const int* __restrict__ xl, const int* __restrict__ yl,
           unsigned char* __restrict__ bits, float* __restrict__ hard, float* __restrict__ dur)
{
  constexpr int PF = 16;
  const int b = blockIdx.x;
  const int lane = threadIdx.x;
  const int xlen = xl[b], ylen = yl[b];
  const int xbase = lane * 8;
  const int xsafe = (xbase < TX - 8) ? xbase : (TX - 8);  // clamped load base (all lanes load)
  const float* lpb = logprob + (size_t)b * TY * TX;
  unsigned char* bb = bits + (size_t)b * TY * 64;

  float prev[8], xm[8];
  #pragma unroll
  for (int j = 0; j < 8; ++j) {
    prev[j] = (xbase + j == 0) ? 0.f : NEGV;
    xm[j] = (xbase + j < xlen) ? 0.f : NEGV;   // additive x-mask (lanes >= TX also masked)
  }

  float4 bufa[PF], bufb[PF];
  #pragma unroll
  for (int p = 0; p < PF; ++p) {
    const float* r = lpb + (size_t)p * TX + xsafe;
    bufa[p] = *(const float4*)r;
    bufb[p] = *(const float4*)(r + 4);
  }

  // PHASE1: per-j causal check (x<=y). PHASE2 (y>=400): always causal.
  auto step = [&](int y, const float4& v0, const float4& v1, bool phase1) {
    float left = __shfl_up(prev[7], 1);
    float v[8] = {v0.x, v0.y, v0.z, v0.w, v1.x, v1.y, v1.z, v1.w};
    unsigned byte = 0;
    float cur[8];
    #pragma unroll
    for (int j = 0; j < 8; ++j) {
      float pl = (j == 0) ? ((xbase == 0) ? NEGV : left) : prev[j - 1];
      byte |= ((pl > prev[j]) ? 1u : 0u) << j;
      float lp = v[j] + xm[j];
      if (phase1) lp = (xbase + j <= y) ? lp : NEGV;
      cur[j] = lp + fmaxf(prev[j], pl);
    }
    bb[(size_t)y * 64 + lane] = (unsigned char)byte;
    #pragma unroll
    for (int j = 0; j < 8; ++j) prev[j] = cur[j];
  };

  int y = 0;
  // phase 1: rows 0..399 (ylen >= 800 always), 25 blocks of 16
  #pragma unroll 1
  for (int blk = 0; blk < 25; ++blk) {
    #pragma unroll
    for (int u = 0; u < PF; ++u) {
      step(y + u, bufa[u], bufb[u], true);
      const float* r = lpb + (size_t)(y + u + PF) * TX + xsafe;  // y+u+16 <= 415 < ylen
      bufa[u] = *(const float4*)r;
      bufb[u] = *(const float4*)(r + 4);
    }
    y += PF;
  }
  // phase 2 full blocks
  const int nfull = 400 + ((ylen - 400) & ~(PF - 1));
  #pragma unroll 1
  for (; y < nfull; y += PF) {
    #pragma unroll
    for (int u = 0; u < PF; ++u) {
      step(y + u, bufa[u], bufb[u], false);
      int yn = y + u + PF;
      if (yn < ylen) {
        const float* r = lpb + (size_t)yn * TX + xsafe;
        bufa[u] = *(const float4*)r;
        bufb[u] = *(const float4*)(r + 4);
      }
    }
  }
  // tail
  #pragma unroll
  for (int u = 0; u < PF; ++u) {
    if (y + u < ylen) step(y + u, bufa[u], bufb[u], false);
  }

  __threadfence();
  __syncthreads();

  // chunked backtrack: all lanes maintain identical scalar state; bits pulled via shfl
  int x = xlen - 1;
  float cnt = 0.f;
  float* hb = hard + (size_t)b * TX * TY;
  float* db = dur + (size_t)b * TX;

  for (int y0 = ylen - 1; y0 >= 0; y0 -= 64) {
    int lo = x - 63; if (lo < 0) lo = 0;
    const int wb = (lo >> 3) & ~3;          // aligned byte base; window [wb, wb+12)
    int ry = y0 - lane;
    unsigned w0 = 0, w1 = 0, w2 = 0;
    if (ry >= 0) {
      const unsigned* rp = (const unsigned*)(bb + (size_t)ry * 64 + wb);
      w0 = rp[0]; w1 = rp[1]; w2 = rp[2];
    }
    int yend = y0 - 63; if (yend < 0) yend = 0;
    for (int yy = y0; yy >= yend; --yy) {
      int k = y0 - yy;
      unsigned s0 = __shfl(w0, k), s1 = __shfl(w1, k), s2 = __shfl(w2, k);
      if (lane == 0) hb[(size_t)x * TY + yy] = 1.0f;
      cnt += 1.f;
      if (yy > 0 && x > 0) {
        int boff = (x >> 3) - wb;
        unsigned wsel = boff < 4 ? s0 : (boff < 8 ? s1 : s2);
        unsigned byte = wsel >> ((boff & 3) * 8);
        bool dec = (x == yy) || ((byte >> (x & 7)) & 1);
        if (dec) { if (lane == 0) db[x] = cnt; cnt = 0.f; x -= 1; }
      }
    }
  }
  if (lane == 0) db[x] = cnt;
}

extern "C" void kernel_launch(void* const* d_in, const int* in_sizes, int n_in,
                              void* d_out, int out_size, void* d_ws, size_t ws_size,
                              hipStream_t stream) {
  const float* mel_x  = (const float*)d_in[0];
  const float* txt_x  = (const float*)d_in[1];
  const float* mel_w1 = (const float*)d_in[2];
  const float* mel_b1 = (const float*)d_in[3];
  const float* mel_w2 = (const float*)d_in[4];
  const float* mel_b2 = (const float*)d_in[5];
  const float* txt_w1 = (const float*)d_in[6];
  const float* txt_b1 = (const float*)d_in[7];
  const float* txt_w2 = (const float*)d_in[8];
  const float* txt_b2 = (const float*)d_in[9];
  const float* wq     = (const float*)d_in[10];
  const float* bq     = (const float*)d_in[11];
  const float* wk     = (const float*)d_in[12];
  const float* bk     = (const float*)d_in[13];
  const int*   xl     = (const int*)d_in[14];
  const int*   yl     = (const int*)d_in[15];

  char* wsb = (char*)d_ws;
  // byte offsets
  constexpr size_t MXH  = 0;                        // 16*1600*96*2   = 4,915,200
  constexpr size_t MXL  = MXH  + 4915200;
  constexpr size_t TXH  = MXL  + 4915200;           // 16*400*512*2   = 6,553,600
  constexpr size_t TXL  = TXH  + 6553600;           // ends 22,937,600
  constexpr size_t TPH  = TXH;                      // txt proj hi (4,915,200) aliases dead TXH/TXL
  constexpr size_t TPL  = TXH  + 4915200;
  constexpr size_t W1MH = TXL  + 6553600;           // 1536*5*96*2  = 1,474,560
  constexpr size_t W1ML = W1MH + 1474560;
  constexpr size_t W2MH = W1ML + 1474560;           // 384*5*768*2  = 2,949,120
  constexpr size_t W2ML = W2MH + 2949120;
  constexpr size_t W1TH = W2ML + 2949120;           // 1536*3*512*2 = 4,718,592
  constexpr size_t W1TL = W1TH + 4718592;
  constexpr size_t W2TH = W1TL + 4718592;           // 384*3*768*2  = 1,769,472
  constexpr size_t W2TL = W2TH + 1769472;
  constexpr size_t WQH  = W2TL + 1769472;           // 384*384*2    = 294,912
  constexpr size_t WQL  = WQH  + 294912;
  constexpr size_t WKH  = WQL  + 294912;
  constexpr size_t WKL  = WKH  + 294912;
  constexpr size_t HH   = WKL  + 294912;            // 16*1600*768*2 = 39,321,600
  constexpr size_t HL   = HH   + 39321600;
  constexpr size_t QB   = HH;                       // q fp32 (39,321,600) aliases dead H hi
  constexpr size_t KTB  = HL;                       // kT fp32 (9,830,400) aliases dead H lo
  constexpr size_t BITS = HL   + 10240000;          // 1,638,400
  constexpr size_t PH   = HL   + 39321600;          // mel proj hi 19,660,800
  constexpr size_t PL   = PH   + 19660800;          // ends ~163.9 MB

  float* out = (float*)d_out;
  float* o_attn = out;
  float* o_logp = out + (size_t)10240000;
  float* o_hard = out + (size_t)20480000;
  float* o_dur  = out + (size_t)30720000;

  hipMemsetAsync(o_hard, 0, (size_t)(10240000 + 6400) * sizeof(float), stream);

  // input splits (channel-padded)
  split_pad_k<<<9600, 256, 0, stream>>>(mel_x, (__bf16*)(wsb + MXH), (__bf16*)(wsb + MXL), 80, 96, 2457600L);
  split_pad_k<<<12800, 256, 0, stream>>>(txt_x, (__bf16*)(wsb + TXH), (__bf16*)(wsb + TXL), 512, 512, 3276800L);
  // weight repack+split
  wsplit_k<<<2880, 256, 0, stream>>>(mel_w1, (__bf16*)(wsb + W1MH), (__bf16*)(wsb + W1ML), 80, 5, 96, 737280L);
  wsplit_k<<<5760, 256, 0, stream>>>(mel_w2, (__bf16*)(wsb + W2MH), (__bf16*)(wsb + W2ML), 768, 5, 768, 1474560L);
  wsplit_k<<<9216, 256, 0, stream>>>(txt_w1, (__bf16*)(wsb + W1TH), (__bf16*)(wsb + W1TL), 512, 3, 512, 2359296L);
  wsplit_k<<<3456, 256, 0, stream>>>(txt_w2, (__bf16*)(wsb + W2TH), (__bf16*)(wsb + W2TL), 768, 3, 768, 884736L);
  wsplit_k<<<576, 256, 0, stream>>>(wq, (__bf16*)(wsb + WQH), (__bf16*)(wsb + WQL), 384, 1, 384, 147456L);
  wsplit_k<<<576, 256, 0, stream>>>(wk, (__bf16*)(wsb + WKH), (__bf16*)(wsb + WKL), 384, 1, 384, 147456L);

  // text pipeline (conv1 -> conv2 overwrites dead TXH/TXL region)
  conv1_mfma<512, 3, 400><<<dim3(4, 12, B), 256, 0, stream>>>(
      (const __bf16*)(wsb + TXH), (const __bf16*)(wsb + TXL),
      (const __bf16*)(wsb + W1TH), (const __bf16*)(wsb + W1TL),
      txt_b1, xl, (__bf16*)(wsb + HH), (__bf16*)(wsb + HL));
  conv2_mfma<768, 3, 400, true, true, false><<<dim3(4, 3, B), 256, 0, stream>>>(
      (const __bf16*)(wsb + HH), (const __bf16*)(wsb + HL),
      (const __bf16*)(wsb + W2TH), (const __bf16*)(wsb + W2TL),
      txt_b2, xl, nullptr, (__bf16*)(wsb + TPH), (__bf16*)(wsb + TPL));

  // mel pipeline
  conv1_mfma<96, 5, 1600><<<dim3(13, 12, B), 256, 0, stream>>>(
      (const __bf16*)(wsb + MXH), (const __bf16*)(wsb + MXL),
      (const __bf16*)(wsb + W1MH), (const __bf16*)(wsb + W1ML),
      mel_b1, yl, (__bf16*)(wsb + HH), (__bf16*)(wsb + HL));
  conv2_mfma<768, 5, 1600, true, true, false><<<dim3(13, 3, B), 256, 0, stream>>>(
      (const __bf16*)(wsb + HH), (const __bf16*)(wsb + HL),
      (const __bf16*)(wsb + W2MH), (const __bf16*)(wsb + W2ML),
      mel_b2, yl, nullptr, (__bf16*)(wsb + PH), (__bf16*)(wsb + PL));

  // q/k projections (MFMA, K=1) — H region now dead, holds q / kT
  conv2_mfma<384, 1, 400, false, false, true><<<dim3(4, 3, B), 256, 0, stream>>>(
      (const __bf16*)(wsb + TPH), (const __bf16*)(wsb + TPL),
      (const __bf16*)(wsb + WKH), (const __bf16*)(wsb + WKL),
      bk, xl, (float*)(wsb + KTB), nullptr, nullptr);
  conv2_mfma<384, 1, 1600, false, false, false><<<dim3(13, 3, B), 256, 0, stream>>>(
      (const __bf16*)(wsb + PH), (const __bf16*)(wsb + PL),
      (const __bf16*)(wsb + WQH), (const __bf16*)(wsb + WQL),
      bq, yl, (float*)(wsb + QB), nullptr, nullptr);

  // attention + MAS
  scores_k<<<dim3(100, B), 512, 0, stream>>>(
      (const float*)(wsb + QB), (const float*)(wsb + KTB), xl, yl, o_attn, o_logp);
  mas_k<<<B, 64, 0, stream>>>(o_logp, xl, yl, (unsigned char*)(wsb + BITS), o_hard, o_dur);
}

// Round 5
// 1822.555 us; speedup vs baseline: 1.0402x; 1.0402x over previous
//
#include <hip/hip_runtime.h>
#include <cstdint>

#define B 16
#define TY 1600
#define TX 400
#define MAS 384
#define HID 768
#define NEGV -1e9f

typedef __bf16 bf16x8 __attribute__((ext_vector_type(8)));
typedef float  f32x4  __attribute__((ext_vector_type(4)));

__device__ __forceinline__ f32x4 mfma16(bf16x8 a, bf16x8 b, f32x4 c) {
  return __builtin_amdgcn_mfma_f32_16x16x32_bf16(a, b, c, 0, 0, 0);
}

// ---------------- fp32 -> bf16 hi/lo split with channel padding ----------------
__global__ void split_pad_k(const float* __restrict__ in, __bf16* __restrict__ oh,
                            __bf16* __restrict__ ol, int CIN, int CINP, long n) {
  long i = (long)blockIdx.x * 256 + threadIdx.x;
  if (i >= n) return;
  long row = i / CINP; int ci = (int)(i - row * CINP);
  float v = (ci < CIN) ? in[row * CIN + ci] : 0.f;
  __bf16 h = (__bf16)v;
  oh[i] = h; ol[i] = (__bf16)(v - (float)h);
}

// ---------------- weight repack+split: w[N][CIN][K] -> oh/ol[N][k*CINP + ci] ----------------
__global__ void wsplit_k(const float* __restrict__ w, __bf16* __restrict__ oh,
                         __bf16* __restrict__ ol, int CIN, int K_, int CINP, long n) {
  long i = (long)blockIdx.x * 256 + threadIdx.x;
  if (i >= n) return;
  long kdspan = (long)K_ * CINP;
  long nn = i / kdspan; int kd = (int)(i - nn * kdspan);
  int k = kd / CINP, ci = kd - k * CINP;
  float v = (ci < CIN) ? w[(nn * CIN + ci) * K_ + k] : 0.f;
  __bf16 h = (__bf16)v;
  oh[i] = h; ol[i] = (__bf16)(v - (float)h);
}

// ---------------- conv1 + ReGLU, split-bf16 MFMA ----------------
template<int CINP, int K, int T>
__global__ __launch_bounds__(256)
void conv1_mfma(const __bf16* __restrict__ xh, const __bf16* __restrict__ xl,
                const __bf16* __restrict__ wh, const __bf16* __restrict__ wl,
                const float* __restrict__ bias, const int* __restrict__ lens,
                __bf16* __restrict__ hh, __bf16* __restrict__ hl)
{
  constexpr int BM = 128, PAD = K / 2, ROWS = BM + K - 1, KD = K * CINP;
  __shared__ float4 xs[8 * ROWS];
  const int b = blockIdx.z, t0 = blockIdx.x * BM, n0 = blockIdx.y * 64;
  const int tid = threadIdx.x, wid = tid >> 6, lane = tid & 63;
  const int wm = wid >> 1, wn = wid & 1, lr = lane & 15, lg = lane >> 4;
  const int len = lens[b];
  const f32x4 Z4 = {0.f, 0.f, 0.f, 0.f};
  f32x4 acc_a[4][2], acc_g[4][2];
  #pragma unroll
  for (int m = 0; m < 4; ++m)
    #pragma unroll
    for (int n = 0; n < 2; ++n) { acc_a[m][n] = Z4; acc_g[m][n] = Z4; }

  #pragma unroll 1
  for (int ci0 = 0; ci0 < CINP; ci0 += 32) {
    __syncthreads();
    for (int e = tid; e < ROWS * 8; e += 256) {
      int row = e >> 3, sc = e & 7, spl = sc >> 2, cg = sc & 3;
      int t = t0 + row - PAD;
      float4 v = {0.f, 0.f, 0.f, 0.f};
      if (t >= 0 && t < len)
        v = *(const float4*)((spl ? xl : xh) + ((size_t)b * T + t) * CINP + ci0 + cg * 8);
      xs[(spl * 4 + cg) * ROWS + row] = v;
    }
    __syncthreads();
    #pragma unroll
    for (int k = 0; k < K; ++k) {
      bf16x8 ah[4], al[4];
      #pragma unroll
      for (int mf = 0; mf < 4; ++mf) {
        int row = wm * 64 + mf * 16 + lr + k;
        ah[mf] = *(const bf16x8*)&xs[lg * ROWS + row];
        al[mf] = *(const bf16x8*)&xs[(4 + lg) * ROWS + row];
      }
      size_t kd = (size_t)k * CINP + ci0 + lg * 8;
      #pragma unroll
      for (int nf = 0; nf < 2; ++nf) {
        int na = n0 + wn * 32 + nf * 16 + lr;
        bf16x8 bah = *(const bf16x8*)(wh + (size_t)na * KD + kd);
        bf16x8 bal = *(const bf16x8*)(wl + (size_t)na * KD + kd);
        bf16x8 bgh = *(const bf16x8*)(wh + (size_t)(na + HID) * KD + kd);
        bf16x8 bgl = *(const bf16x8*)(wl + (size_t)(na + HID) * KD + kd);
        #pragma unroll
        for (int mf = 0; mf < 4; ++mf) {
          acc_a[mf][nf] = mfma16(ah[mf], bah, acc_a[mf][nf]);
          acc_a[mf][nf] = mfma16(ah[mf], bal, acc_a[mf][nf]);
          acc_a[mf][nf] = mfma16(al[mf], bah, acc_a[mf][nf]);
          acc_g[mf][nf] = mfma16(ah[mf], bgh, acc_g[mf][nf]);
          acc_g[mf][nf] = mfma16(ah[mf], bgl, acc_g[mf][nf]);
          acc_g[mf][nf] = mfma16(al[mf], bgh, acc_g[mf][nf]);
        }
      }
    }
  }
  #pragma unroll
  for (int nf = 0; nf < 2; ++nf) {
    int c = n0 + wn * 32 + nf * 16 + lr;
    float ba = bias[c], bg = bias[c + HID];
    #pragma unroll
    for (int mf = 0; mf < 4; ++mf) {
      #pragma unroll
      for (int r = 0; r < 4; ++r) {
        int t = t0 + wm * 64 + mf * 16 + lg * 4 + r;
        if (t < T) {
          float a = acc_a[mf][nf][r] + ba;
          float g = acc_g[mf][nf][r] + bg;
          float v = a * fmaxf(g, 0.f);
          __bf16 vh = (__bf16)v;
          size_t o = ((size_t)b * T + t) * HID + c;
          hh[o] = vh;
          hl[o] = (__bf16)(v - (float)vh);
        }
      }
    }
  }
}

// ---------------- conv2 / linear, split-bf16 MFMA ----------------
template<int CINP, int K, int T, bool MASK, bool SPLITOUT, bool STORET>
__global__ __launch_bounds__(256)
void conv2_mfma(const __bf16* __restrict__ xh, const __bf16* __restrict__ xl,
                const __bf16* __restrict__ wh, const __bf16* __restrict__ wl,
                const float* __restrict__ bias, const int* __restrict__ lens,
                float* __restrict__ out, __bf16* __restrict__ oh, __bf16* __restrict__ ol)
{
  constexpr int BM = 128, PAD = K / 2, ROWS = BM + K - 1, KD = K * CINP;
  __shared__ float4 xs[8 * ROWS];
  const int b = blockIdx.z, t0 = blockIdx.x * BM, n0 = blockIdx.y * 128;
  const int tid = threadIdx.x, wid = tid >> 6, lane = tid & 63;
  const int wm = wid >> 1, wn = wid & 1, lr = lane & 15, lg = lane >> 4;
  const int len = lens[b];
  const f32x4 Z4 = {0.f, 0.f, 0.f, 0.f};
  f32x4 acc[4][4];
  #pragma unroll
  for (int m = 0; m < 4; ++m)
    #pragma unroll
    for (int n = 0; n < 4; ++n) acc[m][n] = Z4;

  #pragma unroll 1
  for (int ci0 = 0; ci0 < CINP; ci0 += 32) {
    __syncthreads();
    for (int e = tid; e < ROWS * 8; e += 256) {
      int row = e >> 3, sc = e & 7, spl = sc >> 2, cg = sc & 3;
      int t = t0 + row - PAD;
      float4 v = {0.f, 0.f, 0.f, 0.f};
      if (t >= 0 && t < len)
        v = *(const float4*)((spl ? xl : xh) + ((size_t)b * T + t) * CINP + ci0 + cg * 8);
      xs[(spl * 4 + cg) * ROWS + row] = v;
    }
    __syncthreads();
    #pragma unroll
    for (int k = 0; k < K; ++k) {
      bf16x8 ah[4], al[4];
      #pragma unroll
      for (int mf = 0; mf < 4; ++mf) {
        int row = wm * 64 + mf * 16 + lr + k;
        ah[mf] = *(const bf16x8*)&xs[lg * ROWS + row];
        al[mf] = *(const bf16x8*)&xs[(4 + lg) * ROWS + row];
      }
      size_t kd = (size_t)k * CINP + ci0 + lg * 8;
      #pragma unroll
      for (int nf = 0; nf < 4; ++nf) {
        int nc = n0 + wn * 64 + nf * 16 + lr;
        bf16x8 bh = *(const bf16x8*)(wh + (size_t)nc * KD + kd);
        bf16x8 bl = *(const bf16x8*)(wl + (size_t)nc * KD + kd);
        #pragma unroll
        for (int mf = 0; mf < 4; ++mf) {
          acc[mf][nf] = mfma16(ah[mf], bh, acc[mf][nf]);
          acc[mf][nf] = mfma16(ah[mf], bl, acc[mf][nf]);
          acc[mf][nf] = mfma16(al[mf], bh, acc[mf][nf]);
        }
      }
    }
  }
  #pragma unroll
  for (int nf = 0; nf < 4; ++nf) {
    int c = n0 + wn * 64 + nf * 16 + lr;
    float bb = bias[c];
    #pragma unroll
    for (int mf = 0; mf < 4; ++mf) {
      #pragma unroll
      for (int r = 0; r < 4; ++r) {
        int t = t0 + wm * 64 + mf * 16 + lg * 4 + r;
        if (t < T) {
          float v = acc[mf][nf][r] + bb;
          if (MASK && t >= len) v = 0.f;
          if (SPLITOUT) {
            __bf16 vh = (__bf16)v;
            size_t o = ((size_t)b * T + t) * MAS + c;
            oh[o] = vh;
            ol[o] = (__bf16)(v - (float)vh);
          } else if (STORET) {
            out[((size_t)b * MAS + c) * T + t] = v;
          } else {
            out[((size_t)b * T + t) * MAS + c] = v;
          }
        }
      }
    }
  }
}

// ---------------- scores + softmax + safe_log ----------------
__global__ __launch_bounds__(512)
void scores_k(const float* __restrict__ q, const float* __restrict__ kT,
              const int* __restrict__ xl, const int* __restrict__ yl,
              float* __restrict__ oattn, float* __restrict__ ologp)
{
  __shared__ float qs[16 * 384];
  __shared__ float tmp[8];
  const int b = blockIdx.y, y0 = blockIdx.x * 16, tid = threadIdx.x;
  for (int e = tid; e < 16 * 384; e += 512)
    qs[e] = q[((size_t)b * TY + (y0 + e / 384)) * 384 + (e - (e / 384) * 384)];
  __syncthreads();
  float acc[16];
  #pragma unroll
  for (int i = 0; i < 16; ++i) acc[i] = 0.f;
  const int x = tid;
  if (x < TX) {
    const float* kb = kT + (size_t)b * MAS * TX + x;
    for (int d = 0; d < 384; d += 4) {
      float k0 = kb[(size_t)(d + 0) * TX], k1 = kb[(size_t)(d + 1) * TX];
      float k2 = kb[(size_t)(d + 2) * TX], k3 = kb[(size_t)(d + 3) * TX];
      #pragma unroll
      for (int yy = 0; yy < 16; ++yy) {
        float4 qv = *(const float4*)&qs[yy * 384 + d];
        acc[yy] = fmaf(qv.x, k0, fmaf(qv.y, k1, fmaf(qv.z, k2, fmaf(qv.w, k3, acc[yy]))));
      }
    }
  }
  const int xlen = xl[b], ylen = yl[b];
  const float scale = 0.05103103630798288f;
  const bool xpad = (x >= xlen);
  const int wv = tid >> 6, ln = tid & 63;
  #pragma unroll 1
  for (int yy = 0; yy < 16; ++yy) {
    int y = y0 + yy;
    float s = -3.0e38f;
    if (x < TX) {
      s = acc[yy] * scale;
      if (xpad && (y >= ylen)) s = -1e-9f;
    }
    float m = s;
    for (int off = 32; off; off >>= 1) m = fmaxf(m, __shfl_xor(m, off));
    if (ln == 0) tmp[wv] = m;
    __syncthreads();
    float mx = fmaxf(fmaxf(fmaxf(tmp[0], tmp[1]), fmaxf(tmp[2], tmp[3])),
                     fmaxf(fmaxf(tmp[4], tmp[5]), fmaxf(tmp[6], tmp[7])));
    __syncthreads();
    float e = (x < TX) ? expf(s - mx) : 0.f;
    float sm = e;
    for (int off = 32; off; off >>= 1) sm += __shfl_xor(sm, off);
    if (ln == 0) tmp[wv] = sm;
    __syncthreads();
    float tot = tmp[0] + tmp[1] + tmp[2] + tmp[3] + tmp[4] + tmp[5] + tmp[6] + tmp[7];
    __syncthreads();
    if (x < TX) {
      float w = e / tot;
      size_t o = ((size_t)b * TY + y) * TX + x;
      oattn[o] = w;
      ologp[o] = logf(w + 1e-6f);
    }
  }
}

// ---------------- MAS: gload_lds-streamed forward DP + chunked wave-parallel backtrack ----------------
// lane l owns x in [8l, 8l+8); bits[b][y][byte=x>>3] bit (x&7) = (v[y-1][x-1] > v[y-1][x])
// Forward reads logprob as a contiguous stream of 16-row (25600 B) groups into a 2-slot LDS ring
// via async global_load_lds; counted s_waitcnt vmcnt(25) keeps one group always in flight (T3/T4).
__global__ __launch_bounds__(64)
void mas_k(const float* __restrict__ logprob, const int* __restrict__ xl, const int* __restrict__ yl,
           unsigned char* __restrict__ bits, float* __restrict__ hard, float* __restrict__ dur)
{
  __shared__ float ring[12800];   // 2 slots x 16 rows x 400 floats = 51200 B
  const int b = blockIdx.x;
  const int lane = threadIdx.x;
  const int xlen = xl[b], ylen = yl[b];
  const int xbase = lane * 8;
  const int lbase = (xbase < 392) ? xbase : 392;   // clamped LDS read base (lanes >=50 masked)
  const float* lpb = logprob + (size_t)b * TY * TX;
  unsigned char* bb = bits + (size_t)b * TY * 64;

  float prev[8], xm[8];
  #pragma unroll
  for (int j = 0; j < 8; ++j) {
    prev[j] = (xbase + j == 0) ? 0.f : NEGV;
    xm[j] = (xbase + j < xlen) ? 0.f : NEGV;   // additive x-mask (covers lanes >= TX too)
  }

  const char* lpc = (const char*)lpb;
  const size_t maxgs = (size_t)TY * 1600 - 25600;   // last in-bounds group start (bytes)
  char* ringc = (char*)ring;
  auto issue_group = [&](int g) {
    size_t gs = (size_t)g * 25600; if (gs > maxgs) gs = maxgs;  // clamp: garbage prefetch, never consumed
    const char* src = lpc + gs + (size_t)lane * 16;
    char* dst = ringc + (g & 1) * 25600;
    #pragma unroll
    for (int i = 0; i < 25; ++i)
      __builtin_amdgcn_global_load_lds(
          (const __attribute__((address_space(1))) void*)(src + i * 1024),
          (__attribute__((address_space(3))) void*)(dst + i * 1024), 16, 0, 0);
  };

  issue_group(0);
  issue_group(1);

  const int ngroups = (ylen + 15) >> 4;
  #pragma unroll 1
  for (int g = 0; g < ngroups; ++g) {
    asm volatile("s_waitcnt vmcnt(25)" ::: "memory");   // group g landed; g+1 stays in flight
    __builtin_amdgcn_sched_barrier(0);
    const float* half = ring + (g & 1) * 6400;
    const int ybase = g * 16;
    const bool phase1 = (ybase < 400);                  // rows 0..399 need the x<=y causal check
    #pragma unroll
    for (int u = 0; u < 16; ++u) {
      const int y = ybase + u;
      const float4 v0 = *(const float4*)&half[u * 400 + lbase];
      const float4 v1 = *(const float4*)&half[u * 400 + lbase + 4];
      float left = __shfl_up(prev[7], 1);
      float v[8] = {v0.x, v0.y, v0.z, v0.w, v1.x, v1.y, v1.z, v1.w};
      unsigned byte = 0;
      float cur[8];
      #pragma unroll
      for (int j = 0; j < 8; ++j) {
        float pl = (j == 0) ? ((xbase == 0) ? NEGV : left) : prev[j - 1];
        byte |= ((pl > prev[j]) ? 1u : 0u) << j;
        float lp = v[j] + xm[j];
        if (phase1) lp = (xbase + j <= y) ? lp : NEGV;
        cur[j] = lp + fmaxf(prev[j], pl);
      }
      bb[(size_t)y * 64 + lane] = (unsigned char)byte;  // rows >= ylen write garbage, never read
      #pragma unroll
      for (int j = 0; j < 8; ++j) prev[j] = cur[j];
    }
    __builtin_amdgcn_sched_barrier(0);                  // keep next issue after this group's ds_reads
    issue_group(g + 2);                                 // overwrites the slot just consumed
  }

  __threadfence();
  __syncthreads();

  // chunked backtrack: all lanes maintain identical scalar state; bits pulled via shfl
  int x = xlen - 1;
  float cnt = 0.f;
  float* hb = hard + (size_t)b * TX * TY;
  float* db = dur + (size_t)b * TX;

  for (int y0 = ylen - 1; y0 >= 0; y0 -= 64) {
    int lo = x - 63; if (lo < 0) lo = 0;
    const int wb = (lo >> 3) & ~3;          // aligned byte base; window [wb, wb+12)
    int ry = y0 - lane;
    unsigned w0 = 0, w1 = 0, w2 = 0;
    if (ry >= 0) {
      const unsigned* rp = (const unsigned*)(bb + (size_t)ry * 64 + wb);
      w0 = rp[0]; w1 = rp[1]; w2 = rp[2];
    }
    int yend = y0 - 63; if (yend < 0) yend = 0;
    for (int yy = y0; yy >= yend; --yy) {
      int k = y0 - yy;
      unsigned s0 = __shfl(w0, k), s1 = __shfl(w1, k), s2 = __shfl(w2, k);
      if (lane == 0) hb[(size_t)x * TY + yy] = 1.0f;
      cnt += 1.f;
      if (yy > 0 && x > 0) {
        int boff = (x >> 3) - wb;
        unsigned wsel = boff < 4 ? s0 : (boff < 8 ? s1 : s2);
        unsigned byte = wsel >> ((boff & 3) * 8);
        bool dec = (x == yy) || ((byte >> (x & 7)) & 1);
        if (dec) { if (lane == 0) db[x] = cnt; cnt = 0.f; x -= 1; }
      }
    }
  }
  if (lane == 0) db[x] = cnt;
}

extern "C" void kernel_launch(void* const* d_in, const int* in_sizes, int n_in,
                              void* d_out, int out_size, void* d_ws, size_t ws_size,
                              hipStream_t stream) {
  const float* mel_x  = (const float*)d_in[0];
  const float* txt_x  = (const float*)d_in[1];
  const float* mel_w1 = (const float*)d_in[2];
  const float* mel_b1 = (const float*)d_in[3];
  const float* mel_w2 = (const float*)d_in[4];
  const float* mel_b2 = (const float*)d_in[5];
  const float* txt_w1 = (const float*)d_in[6];
  const float* txt_b1 = (const float*)d_in[7];
  const float* txt_w2 = (const float*)d_in[8];
  const float* txt_b2 = (const float*)d_in[9];
  const float* wq     = (const float*)d_in[10];
  const float* bq     = (const float*)d_in[11];
  const float* wk     = (const float*)d_in[12];
  const float* bk     = (const float*)d_in[13];
  const int*   xl     = (const int*)d_in[14];
  const int*   yl     = (const int*)d_in[15];

  char* wsb = (char*)d_ws;
  // byte offsets
  constexpr size_t MXH  = 0;                        // 16*1600*96*2   = 4,915,200
  constexpr size_t MXL  = MXH  + 4915200;
  constexpr size_t TXH  = MXL  + 4915200;           // 16*400*512*2   = 6,553,600
  constexpr size_t TXL  = TXH  + 6553600;           // ends 22,937,600
  constexpr size_t TPH  = TXH;                      // txt proj hi (4,915,200) aliases dead TXH/TXL
  constexpr size_t TPL  = TXH  + 4915200;
  constexpr size_t W1MH = TXL  + 6553600;           // 1536*5*96*2  = 1,474,560
  constexpr size_t W1ML = W1MH + 1474560;
  constexpr size_t W2MH = W1ML + 1474560;           // 384*5*768*2  = 2,949,120
  constexpr size_t W2ML = W2MH + 2949120;
  constexpr size_t W1TH = W2ML + 2949120;           // 1536*3*512*2 = 4,718,592
  constexpr size_t W1TL = W1TH + 4718592;
  constexpr size_t W2TH = W1TL + 4718592;           // 384*3*768*2  = 1,769,472
  constexpr size_t W2TL = W2TH + 1769472;
  constexpr size_t WQH  = W2TL + 1769472;           // 384*384*2    = 294,912
  constexpr size_t WQL  = WQH  + 294912;
  constexpr size_t WKH  = WQL  + 294912;
  constexpr size_t WKL  = WKH  + 294912;
  constexpr size_t HH   = WKL  + 294912;            // 16*1600*768*2 = 39,321,600
  constexpr size_t HL   = HH   + 39321600;
  constexpr size_t QB   = HH;                       // q fp32 (39,321,600) aliases dead H hi
  constexpr size_t KTB  = HL;                       // kT fp32 (9,830,400) aliases dead H lo
  constexpr size_t BITS = HL   + 10240000;          // 1,638,400
  constexpr size_t PH   = HL   + 39321600;          // mel proj hi 19,660,800
  constexpr size_t PL   = PH   + 19660800;          // ends ~163.9 MB

  float* out = (float*)d_out;
  float* o_attn = out;
  float* o_logp = out + (size_t)10240000;
  float* o_hard = out + (size_t)20480000;
  float* o_dur  = out + (size_t)30720000;

  hipMemsetAsync(o_hard, 0, (size_t)(10240000 + 6400) * sizeof(float), stream);

  // input splits (channel-padded)
  split_pad_k<<<9600, 256, 0, stream>>>(mel_x, (__bf16*)(wsb + MXH), (__bf16*)(wsb + MXL), 80, 96, 2457600L);
  split_pad_k<<<12800, 256, 0, stream>>>(txt_x, (__bf16*)(wsb + TXH), (__bf16*)(wsb + TXL), 512, 512, 3276800L);
  // weight repack+split
  wsplit_k<<<2880, 256, 0, stream>>>(mel_w1, (__bf16*)(wsb + W1MH), (__bf16*)(wsb + W1ML), 80, 5, 96, 737280L);
  wsplit_k<<<5760, 256, 0, stream>>>(mel_w2, (__bf16*)(wsb + W2MH), (__bf16*)(wsb + W2ML), 768, 5, 768, 1474560L);
  wsplit_k<<<9216, 256, 0, stream>>>(txt_w1, (__bf16*)(wsb + W1TH), (__bf16*)(wsb + W1TL), 512, 3, 512, 2359296L);
  wsplit_k<<<3456, 256, 0, stream>>>(txt_w2, (__bf16*)(wsb + W2TH), (__bf16*)(wsb + W2TL), 768, 3, 768, 884736L);
  wsplit_k<<<576, 256, 0, stream>>>(wq, (__bf16*)(wsb + WQH), (__bf16*)(wsb + WQL), 384, 1, 384, 147456L);
  wsplit_k<<<576, 256, 0, stream>>>(wk, (__bf16*)(wsb + WKH), (__bf16*)(wsb + WKL), 384, 1, 384, 147456L);

  // text pipeline (conv1 -> conv2 overwrites dead TXH/TXL region)
  conv1_mfma<512, 3, 400><<<dim3(4, 12, B), 256, 0, stream>>>(
      (const __bf16*)(wsb + TXH), (const __bf16*)(wsb + TXL),
      (const __bf16*)(wsb + W1TH), (const __bf16*)(wsb + W1TL),
      txt_b1, xl, (__bf16*)(wsb + HH), (__bf16*)(wsb + HL));
  conv2_mfma<768, 3, 400, true, true, false><<<dim3(4, 3, B), 256, 0, stream>>>(
      (const __bf16*)(wsb + HH), (const __bf16*)(wsb + HL),
      (const __bf16*)(wsb + W2TH), (const __bf16*)(wsb + W2TL),
      txt_b2, xl, nullptr, (__bf16*)(wsb + TPH), (__bf16*)(wsb + TPL));

  // mel pipeline
  conv1_mfma<96, 5, 1600><<<dim3(13, 12, B), 256, 0, stream>>>(
      (const __bf16*)(wsb + MXH), (const __bf16*)(wsb + MXL),
      (const __bf16*)(wsb + W1MH), (const __bf16*)(wsb + W1ML),
      mel_b1, yl, (__bf16*)(wsb + HH), (__bf16*)(wsb + HL));
  conv2_mfma<768, 5, 1600, true, true, false><<<dim3(13, 3, B), 256, 0, stream>>>(
      (const __bf16*)(wsb + HH), (const __bf16*)(wsb + HL),
      (const __bf16*)(wsb + W2MH), (const __bf16*)(wsb + W2ML),
      mel_b2, yl, nullptr, (__bf16*)(wsb + PH), (__bf16*)(wsb + PL));

  // q/k projections (MFMA, K=1) — H region now dead, holds q / kT
  conv2_mfma<384, 1, 400, false, false, true><<<dim3(4, 3, B), 256, 0, stream>>>(
      (const __bf16*)(wsb + TPH), (const __bf16*)(wsb + TPL),
      (const __bf16*)(wsb + WKH), (const __bf16*)(wsb + WKL),
      bk, xl, (float*)(wsb + KTB), nullptr, nullptr);
  conv2_mfma<384, 1, 1600, false, false, false><<<dim3(13, 3, B), 256, 0, stream>>>(
      (const __bf16*)(wsb + PH), (const __bf16*)(wsb + PL),
      (const __bf16*)(wsb + WQH), (const __bf16*)(wsb + WQL),
      bq, yl, (float*)(wsb + QB), nullptr, nullptr);

  // attention + MAS
  scores_k<<<dim3(100, B), 512, 0, stream>>>(
      (const float*)(wsb + QB), (const float*)(wsb + KTB), xl, yl, o_attn, o_logp);
  mas_k<<<B, 64, 0, stream>>>(o_logp, xl, yl, (unsigned char*)(wsb + BITS), o_hard, o_dur);
}

// Round 6
// 1778.187 us; speedup vs baseline: 1.0661x; 1.0250x over previous
//
#include <hip/hip_runtime.h>
#include <cstdint>

#define B 16
#define TY 1600
#define TX 400
#define MAS 384
#define HID 768
#define NEGV -1e9f

typedef __bf16 bf16x8 __attribute__((ext_vector_type(8)));
typedef float  f32x4  __attribute__((ext_vector_type(4)));

__device__ __forceinline__ f32x4 mfma16(bf16x8 a, bf16x8 b, f32x4 c) {
  return __builtin_amdgcn_mfma_f32_16x16x32_bf16(a, b, c, 0, 0, 0);
}

// ---------------- fp32 -> bf16 hi/lo split with channel padding ----------------
__global__ void split_pad_k(const float* __restrict__ in, __bf16* __restrict__ oh,
                            __bf16* __restrict__ ol, int CIN, int CINP, long n) {
  long i = (long)blockIdx.x * 256 + threadIdx.x;
  if (i >= n) return;
  long row = i / CINP; int ci = (int)(i - row * CINP);
  float v = (ci < CIN) ? in[row * CIN + ci] : 0.f;
  __bf16 h = (__bf16)v;
  oh[i] = h; ol[i] = (__bf16)(v - (float)h);
}

// ---------------- weight repack+split: w[N][CIN][K] -> oh/ol[N][k*CINP + ci] ----------------
__global__ void wsplit_k(const float* __restrict__ w, __bf16* __restrict__ oh,
                         __bf16* __restrict__ ol, int CIN, int K_, int CINP, long n) {
  long i = (long)blockIdx.x * 256 + threadIdx.x;
  if (i >= n) return;
  long kdspan = (long)K_ * CINP;
  long nn = i / kdspan; int kd = (int)(i - nn * kdspan);
  int k = kd / CINP, ci = kd - k * CINP;
  float v = (ci < CIN) ? w[(nn * CIN + ci) * K_ + k] : 0.f;
  __bf16 h = (__bf16)v;
  oh[i] = h; ol[i] = (__bf16)(v - (float)h);
}

// ---------------- conv1 + ReGLU, split-bf16 MFMA ----------------
template<int CINP, int K, int T>
__global__ __launch_bounds__(256)
void conv1_mfma(const __bf16* __restrict__ xh, const __bf16* __restrict__ xl,
                const __bf16* __restrict__ wh, const __bf16* __restrict__ wl,
                const float* __restrict__ bias, const int* __restrict__ lens,
                __bf16* __restrict__ hh, __bf16* __restrict__ hl)
{
  constexpr int BM = 128, PAD = K / 2, ROWS = BM + K - 1, KD = K * CINP;
  __shared__ float4 xs[8 * ROWS];
  const int b = blockIdx.z, t0 = blockIdx.x * BM, n0 = blockIdx.y * 64;
  const int tid = threadIdx.x, wid = tid >> 6, lane = tid & 63;
  const int wm = wid >> 1, wn = wid & 1, lr = lane & 15, lg = lane >> 4;
  const int len = lens[b];
  const f32x4 Z4 = {0.f, 0.f, 0.f, 0.f};
  f32x4 acc_a[4][2], acc_g[4][2];
  #pragma unroll
  for (int m = 0; m < 4; ++m)
    #pragma unroll
    for (int n = 0; n < 2; ++n) { acc_a[m][n] = Z4; acc_g[m][n] = Z4; }

  #pragma unroll 1
  for (int ci0 = 0; ci0 < CINP; ci0 += 32) {
    __syncthreads();
    for (int e = tid; e < ROWS * 8; e += 256) {
      int row = e >> 3, sc = e & 7, spl = sc >> 2, cg = sc & 3;
      int t = t0 + row - PAD;
      float4 v = {0.f, 0.f, 0.f, 0.f};
      if (t >= 0 && t < len)
        v = *(const float4*)((spl ? xl : xh) + ((size_t)b * T + t) * CINP + ci0 + cg * 8);
      xs[(spl * 4 + cg) * ROWS + row] = v;
    }
    __syncthreads();
    #pragma unroll
    for (int k = 0; k < K; ++k) {
      bf16x8 ah[4], al[4];
      #pragma unroll
      for (int mf = 0; mf < 4; ++mf) {
        int row = wm * 64 + mf * 16 + lr + k;
        ah[mf] = *(const bf16x8*)&xs[lg * ROWS + row];
        al[mf] = *(const bf16x8*)&xs[(4 + lg) * ROWS + row];
      }
      size_t kd = (size_t)k * CINP + ci0 + lg * 8;
      #pragma unroll
      for (int nf = 0; nf < 2; ++nf) {
        int na = n0 + wn * 32 + nf * 16 + lr;
        bf16x8 bah = *(const bf16x8*)(wh + (size_t)na * KD + kd);
        bf16x8 bal = *(const bf16x8*)(wl + (size_t)na * KD + kd);
        bf16x8 bgh = *(const bf16x8*)(wh + (size_t)(na + HID) * KD + kd);
        bf16x8 bgl = *(const bf16x8*)(wl + (size_t)(na + HID) * KD + kd);
        #pragma unroll
        for (int mf = 0; mf < 4; ++mf) {
          acc_a[mf][nf] = mfma16(ah[mf], bah, acc_a[mf][nf]);
          acc_a[mf][nf] = mfma16(ah[mf], bal, acc_a[mf][nf]);
          acc_a[mf][nf] = mfma16(al[mf], bah, acc_a[mf][nf]);
          acc_g[mf][nf] = mfma16(ah[mf], bgh, acc_g[mf][nf]);
          acc_g[mf][nf] = mfma16(ah[mf], bgl, acc_g[mf][nf]);
          acc_g[mf][nf] = mfma16(al[mf], bgh, acc_g[mf][nf]);
        }
      }
    }
  }
  #pragma unroll
  for (int nf = 0; nf < 2; ++nf) {
    int c = n0 + wn * 32 + nf * 16 + lr;
    float ba = bias[c], bg = bias[c + HID];
    #pragma unroll
    for (int mf = 0; mf < 4; ++mf) {
      #pragma unroll
      for (int r = 0; r < 4; ++r) {
        int t = t0 + wm * 64 + mf * 16 + lg * 4 + r;
        if (t < T) {
          float a = acc_a[mf][nf][r] + ba;
          float g = acc_g[mf][nf][r] + bg;
          float v = a * fmaxf(g, 0.f);
          __bf16 vh = (__bf16)v;
          size_t o = ((size_t)b * T + t) * HID + c;
          hh[o] = vh;
          hl[o] = (__bf16)(v - (float)vh);
        }
      }
    }
  }
}

// ---------------- conv2 / linear, split-bf16 MFMA ----------------
template<int CINP, int K, int T, bool MASK, bool SPLITOUT, bool STORET>
__global__ __launch_bounds__(256)
void conv2_mfma(const __bf16* __restrict__ xh, const __bf16* __restrict__ xl,
                const __bf16* __restrict__ wh, const __bf16* __restrict__ wl,
                const float* __restrict__ bias, const int* __restrict__ lens,
                float* __restrict__ out, __bf16* __restrict__ oh, __bf16* __restrict__ ol)
{
  constexpr int BM = 128, PAD = K / 2, ROWS = BM + K - 1, KD = K * CINP;
  __shared__ float4 xs[8 * ROWS];
  const int b = blockIdx.z, t0 = blockIdx.x * BM, n0 = blockIdx.y * 128;
  const int tid = threadIdx.x, wid = tid >> 6, lane = tid & 63;
  const int wm = wid >> 1, wn = wid & 1, lr = lane & 15, lg = lane >> 4;
  const int len = lens[b];
  const f32x4 Z4 = {0.f, 0.f, 0.f, 0.f};
  f32x4 acc[4][4];
  #pragma unroll
  for (int m = 0; m < 4; ++m)
    #pragma unroll
    for (int n = 0; n < 4; ++n) acc[m][n] = Z4;

  #pragma unroll 1
  for (int ci0 = 0; ci0 < CINP; ci0 += 32) {
    __syncthreads();
    for (int e = tid; e < ROWS * 8; e += 256) {
      int row = e >> 3, sc = e & 7, spl = sc >> 2, cg = sc & 3;
      int t = t0 + row - PAD;
      float4 v = {0.f, 0.f, 0.f, 0.f};
      if (t >= 0 && t < len)
        v = *(const float4*)((spl ? xl : xh) + ((size_t)b * T + t) * CINP + ci0 + cg * 8);
      xs[(spl * 4 + cg) * ROWS + row] = v;
    }
    __syncthreads();
    #pragma unroll
    for (int k = 0; k < K; ++k) {
      bf16x8 ah[4], al[4];
      #pragma unroll
      for (int mf = 0; mf < 4; ++mf) {
        int row = wm * 64 + mf * 16 + lr + k;
        ah[mf] = *(const bf16x8*)&xs[lg * ROWS + row];
        al[mf] = *(const bf16x8*)&xs[(4 + lg) * ROWS + row];
      }
      size_t kd = (size_t)k * CINP + ci0 + lg * 8;
      #pragma unroll
      for (int nf = 0; nf < 4; ++nf) {
        int nc = n0 + wn * 64 + nf * 16 + lr;
        bf16x8 bh = *(const bf16x8*)(wh + (size_t)nc * KD + kd);
        bf16x8 bl = *(const bf16x8*)(wl + (size_t)nc * KD + kd);
        #pragma unroll
        for (int mf = 0; mf < 4; ++mf) {
          acc[mf][nf] = mfma16(ah[mf], bh, acc[mf][nf]);
          acc[mf][nf] = mfma16(ah[mf], bl, acc[mf][nf]);
          acc[mf][nf] = mfma16(al[mf], bh, acc[mf][nf]);
        }
      }
    }
  }
  #pragma unroll
  for (int nf = 0; nf < 4; ++nf) {
    int c = n0 + wn * 64 + nf * 16 + lr;
    float bb = bias[c];
    #pragma unroll
    for (int mf = 0; mf < 4; ++mf) {
      #pragma unroll
      for (int r = 0; r < 4; ++r) {
        int t = t0 + wm * 64 + mf * 16 + lg * 4 + r;
        if (t < T) {
          float v = acc[mf][nf][r] + bb;
          if (MASK && t >= len) v = 0.f;
          if (SPLITOUT) {
            __bf16 vh = (__bf16)v;
            size_t o = ((size_t)b * T + t) * MAS + c;
            oh[o] = vh;
            ol[o] = (__bf16)(v - (float)vh);
          } else if (STORET) {
            out[((size_t)b * MAS + c) * T + t] = v;
          } else {
            out[((size_t)b * T + t) * MAS + c] = v;
          }
        }
      }
    }
  }
}

// ---------------- scores + softmax + safe_log ----------------
__global__ __launch_bounds__(512)
void scores_k(const float* __restrict__ q, const float* __restrict__ kT,
              const int* __restrict__ xl, const int* __restrict__ yl,
              float* __restrict__ oattn, float* __restrict__ ologp)
{
  __shared__ float qs[16 * 384];
  __shared__ float tmp[8];
  const int b = blockIdx.y, y0 = blockIdx.x * 16, tid = threadIdx.x;
  for (int e = tid; e < 16 * 384; e += 512)
    qs[e] = q[((size_t)b * TY + (y0 + e / 384)) * 384 + (e - (e / 384) * 384)];
  __syncthreads();
  float acc[16];
  #pragma unroll
  for (int i = 0; i < 16; ++i) acc[i] = 0.f;
  const int x = tid;
  if (x < TX) {
    const float* kb = kT + (size_t)b * MAS * TX + x;
    for (int d = 0; d < 384; d += 4) {
      float k0 = kb[(size_t)(d + 0) * TX], k1 = kb[(size_t)(d + 1) * TX];
      float k2 = kb[(size_t)(d + 2) * TX], k3 = kb[(size_t)(d + 3) * TX];
      #pragma unroll
      for (int yy = 0; yy < 16; ++yy) {
        float4 qv = *(const float4*)&qs[yy * 384 + d];
        acc[yy] = fmaf(qv.x, k0, fmaf(qv.y, k1, fmaf(qv.z, k2, fmaf(qv.w, k3, acc[yy]))));
      }
    }
  }
  const int xlen = xl[b], ylen = yl[b];
  const float scale = 0.05103103630798288f;
  const bool xpad = (x >= xlen);
  const int wv = tid >> 6, ln = tid & 63;
  #pragma unroll 1
  for (int yy = 0; yy < 16; ++yy) {
    int y = y0 + yy;
    float s = -3.0e38f;
    if (x < TX) {
      s = acc[yy] * scale;
      if (xpad && (y >= ylen)) s = -1e-9f;
    }
    float m = s;
    for (int off = 32; off; off >>= 1) m = fmaxf(m, __shfl_xor(m, off));
    if (ln == 0) tmp[wv] = m;
    __syncthreads();
    float mx = fmaxf(fmaxf(fmaxf(tmp[0], tmp[1]), fmaxf(tmp[2], tmp[3])),
                     fmaxf(fmaxf(tmp[4], tmp[5]), fmaxf(tmp[6], tmp[7])));
    __syncthreads();
    float e = (x < TX) ? expf(s - mx) : 0.f;
    float sm = e;
    for (int off = 32; off; off >>= 1) sm += __shfl_xor(sm, off);
    if (ln == 0) tmp[wv] = sm;
    __syncthreads();
    float tot = tmp[0] + tmp[1] + tmp[2] + tmp[3] + tmp[4] + tmp[5] + tmp[6] + tmp[7];
    __syncthreads();
    if (x < TX) {
      float w = e / tot;
      size_t o = ((size_t)b * TY + y) * TX + x;
      oattn[o] = w;
      ologp[o] = logf(w + 1e-6f);
    }
  }
}

// ---------------- MAS forward: 4-row blocked DP, halo windows, no per-row shfl ----------------
// lane l owns positions [8l, 8l+8) with a 4-wide left halo [8l-4, 8l).
// Cross-lane handoff (4 shfl_up) once per 4-row block. Bits layout: bits[b][y][byte=x>>3].
#define MAS_LD(blkv, buf) do {                                           \
    int base_ = (blkv) * 4;                                              \
    _Pragma("unroll")                                                    \
    for (int d_ = 0; d_ < 4; ++d_) {                                     \
      int yr_ = base_ + d_; if (yr_ > TY - 1) yr_ = TY - 1;              \
      const float* r_ = lpb + (size_t)yr_ * TX;                          \
      buf[d_ * 3 + 0] = *(const float4*)(r_ + lb0);                      \
      buf[d_ * 3 + 1] = *(const float4*)(r_ + lb1);                      \
      buf[d_ * 3 + 2] = *(const float4*)(r_ + lb2);                      \
    } } while (0)

#define MAS_BLK(blkv, buf) do {                                          \
    float h0 = __shfl_up(w[8], 1),  h1 = __shfl_up(w[9], 1);             \
    float h2 = __shfl_up(w[10], 1), h3 = __shfl_up(w[11], 1);            \
    w[0] = lane ? h0 : NEGV; w[1] = lane ? h1 : NEGV;                    \
    w[2] = lane ? h2 : NEGV; w[3] = lane ? h3 : NEGV;                    \
    const int y0_ = (blkv) * 4;                                          \
    const bool ph1_ = (y0_ < TX);                                        \
    _Pragma("unroll")                                                    \
    for (int d_ = 0; d_ < 4; ++d_) {                                     \
      const int y_ = y0_ + d_;                                           \
      float lp[12];                                                      \
      _Pragma("unroll")                                                  \
      for (int k_ = 0; k_ < 3; ++k_) {                                   \
        float4 v_ = buf[d_ * 3 + k_];                                    \
        lp[k_*4+0] = v_.x + wxm[k_*4+0]; lp[k_*4+1] = v_.y + wxm[k_*4+1];\
        lp[k_*4+2] = v_.z + wxm[k_*4+2]; lp[k_*4+3] = v_.w + wxm[k_*4+3];\
      }                                                                  \
      if (ph1_) {                                                        \
        int c_ = y_ - p0;                                                \
        _Pragma("unroll")                                                \
        for (int i_ = 0; i_ < 12; ++i_) lp[i_] = (i_ <= c_) ? lp[i_] : NEGV; \
      }                                                                  \
      unsigned byte_ = 0;                                                \
      _Pragma("unroll")                                                  \
      for (int j_ = 0; j_ < 8; ++j_)                                     \
        byte_ |= (w[j_ + 3] > w[j_ + 4]) ? (1u << j_) : 0u;              \
      float nw[12];                                                      \
      nw[0] = lp[0] + w[0];                                              \
      _Pragma("unroll")                                                  \
      for (int i_ = 1; i_ < 12; ++i_) nw[i_] = lp[i_] + fmaxf(w[i_], w[i_ - 1]); \
      bb[(size_t)y_ * 64 + lane] = (unsigned char)byte_;                 \
      _Pragma("unroll")                                                  \
      for (int i_ = 0; i_ < 12; ++i_) w[i_] = nw[i_];                    \
    } } while (0)

__global__ __launch_bounds__(64)
void mas_fwd(const float* __restrict__ logprob, const int* __restrict__ xl,
             const int* __restrict__ yl, unsigned char* __restrict__ bits)
{
  const int b = blockIdx.x;
  const int lane = threadIdx.x;
  const int xlen = xl[b], ylen = yl[b];
  const float* lpb = logprob + (size_t)b * TY * TX;
  unsigned char* bb = bits + (size_t)b * TY * 64;
  const int p0 = lane * 8 - 4;
  int t;
  t = p0;     if (t < 0) t = 0; if (t > 396) t = 396; const int lb0 = t;
  t = p0 + 4; if (t < 0) t = 0; if (t > 396) t = 396; const int lb1 = t;
  t = p0 + 8; if (t < 0) t = 0; if (t > 396) t = 396; const int lb2 = t;

  float w[12], wxm[12];
  #pragma unroll
  for (int i = 0; i < 12; ++i) {
    int p = p0 + i;
    wxm[i] = (p >= 0 && p < xlen) ? 0.f : NEGV;
    w[i] = (p == 0) ? 0.f : NEGV;
  }

  float4 bufA[12], bufB[12];
  MAS_LD(0, bufA);
  MAS_LD(1, bufB);
  const int nblk = (ylen + 3) >> 2;
  int blk = 0;
  #pragma unroll 1
  for (; blk + 1 < nblk; blk += 2) {
    MAS_BLK(blk, bufA);
    MAS_LD(blk + 2, bufA);
    MAS_BLK(blk + 1, bufB);
    MAS_LD(blk + 3, bufB);
  }
  if (blk < nblk) MAS_BLK(blk, bufA);
}

// ---------------- MAS backtrack: uniform scalar walk via readlane, run-painted output ----------------
__global__ __launch_bounds__(64)
void mas_bt(const unsigned char* __restrict__ bits, const int* __restrict__ xl,
            const int* __restrict__ yl, float* __restrict__ hard, float* __restrict__ dur)
{
  const int b = blockIdx.x;
  const int lane = threadIdx.x;
  const int xlen = xl[b], ylen = yl[b];
  const unsigned char* bb = bits + (size_t)b * TY * 64;
  float* hb = hard + (size_t)b * TX * TY;
  float* db = dur + (size_t)b * TX;

  int x = xlen - 1;
  int cnt = 0;
  #pragma unroll 1
  for (int ycur = ylen - 1; ycur >= 0; ycur -= 64) {
    int lo = x - 63; if (lo < 0) lo = 0;
    const int wb = (lo >> 3) & ~3;                    // window bytes [wb, wb+12)
    int ry = ycur - lane;
    unsigned w0 = 0, w1 = 0, w2 = 0;
    if (ry >= 0) {
      const unsigned* rp = (const unsigned*)(bb + (size_t)ry * 64 + wb);
      w0 = rp[0]; w1 = rp[1]; w2 = rp[2];
    }
    const int rows = (ycur + 1 < 64) ? (ycur + 1) : 64;
    #pragma unroll 1
    for (int s = 0; s < rows; s += 8) {
      const int cnt8 = (rows - s < 8) ? (rows - s) : 8;
      unsigned r0[8], r1[8], r2[8];
      #pragma unroll
      for (int u = 0; u < 8; ++u) {
        r0[u] = (unsigned)__builtin_amdgcn_readlane((int)w0, s + u);
        r1[u] = (unsigned)__builtin_amdgcn_readlane((int)w1, s + u);
        r2[u] = (unsigned)__builtin_amdgcn_readlane((int)w2, s + u);
      }
      #pragma unroll
      for (int u = 0; u < 8; ++u) {
        if (u < cnt8) {
          const int yy = ycur - s - u;
          ++cnt;
          if (yy > 0 && x > 0) {
            const int boff = (x >> 3) - wb;
            const unsigned word = (boff < 4) ? r0[u] : ((boff < 8) ? r1[u] : r2[u]);
            const unsigned byte = word >> ((boff & 3) * 8);
            if ((x == yy) || ((byte >> (x & 7)) & 1)) {
              for (int q = lane; q < cnt; q += 64) hb[(size_t)x * TY + yy + q] = 1.0f;
              if (lane == 0) db[x] = (float)cnt;
              cnt = 0;
              --x;
            }
          }
        }
      }
    }
  }
  for (int q = lane; q < cnt; q += 64) hb[(size_t)x * TY + q] = 1.0f;
  if (lane == 0) db[x] = (float)cnt;
}

extern "C" void kernel_launch(void* const* d_in, const int* in_sizes, int n_in,
                              void* d_out, int out_size, void* d_ws, size_t ws_size,
                              hipStream_t stream) {
  const float* mel_x  = (const float*)d_in[0];
  const float* txt_x  = (const float*)d_in[1];
  const float* mel_w1 = (const float*)d_in[2];
  const float* mel_b1 = (const float*)d_in[3];
  const float* mel_w2 = (const float*)d_in[4];
  const float* mel_b2 = (const float*)d_in[5];
  const float* txt_w1 = (const float*)d_in[6];
  const float* txt_b1 = (const float*)d_in[7];
  const float* txt_w2 = (const float*)d_in[8];
  const float* txt_b2 = (const float*)d_in[9];
  const float* wq     = (const float*)d_in[10];
  const float* bq     = (const float*)d_in[11];
  const float* wk     = (const float*)d_in[12];
  const float* bk     = (const float*)d_in[13];
  const int*   xl     = (const int*)d_in[14];
  const int*   yl     = (const int*)d_in[15];

  char* wsb = (char*)d_ws;
  // byte offsets
  constexpr size_t MXH  = 0;                        // 16*1600*96*2   = 4,915,200
  constexpr size_t MXL  = MXH  + 4915200;
  constexpr size_t TXH  = MXL  + 4915200;           // 16*400*512*2   = 6,553,600
  constexpr size_t TXL  = TXH  + 6553600;           // ends 22,937,600
  constexpr size_t TPH  = TXH;                      // txt proj hi (4,915,200) aliases dead TXH/TXL
  constexpr size_t TPL  = TXH  + 4915200;
  constexpr size_t W1MH = TXL  + 6553600;           // 1536*5*96*2  = 1,474,560
  constexpr size_t W1ML = W1MH + 1474560;
  constexpr size_t W2MH = W1ML + 1474560;           // 384*5*768*2  = 2,949,120
  constexpr size_t W2ML = W2MH + 2949120;
  constexpr size_t W1TH = W2ML + 2949120;           // 1536*3*512*2 = 4,718,592
  constexpr size_t W1TL = W1TH + 4718592;
  constexpr size_t W2TH = W1TL + 4718592;           // 384*3*768*2  = 1,769,472
  constexpr size_t W2TL = W2TH + 1769472;
  constexpr size_t WQH  = W2TL + 1769472;           // 384*384*2    = 294,912
  constexpr size_t WQL  = WQH  + 294912;
  constexpr size_t WKH  = WQL  + 294912;
  constexpr size_t WKL  = WKH  + 294912;
  constexpr size_t HH   = WKL  + 294912;            // 16*1600*768*2 = 39,321,600
  constexpr size_t HL   = HH   + 39321600;
  constexpr size_t QB   = HH;                       // q fp32 (39,321,600) aliases dead H hi
  constexpr size_t KTB  = HL;                       // kT fp32 (9,830,400) aliases dead H lo
  constexpr size_t BITS = HL   + 10240000;          // 1,638,400
  constexpr size_t PH   = HL   + 39321600;          // mel proj hi 19,660,800
  constexpr size_t PL   = PH   + 19660800;          // ends ~163.9 MB

  float* out = (float*)d_out;
  float* o_attn = out;
  float* o_logp = out + (size_t)10240000;
  float* o_hard = out + (size_t)20480000;
  float* o_dur  = out + (size_t)30720000;

  hipMemsetAsync(o_hard, 0, (size_t)(10240000 + 6400) * sizeof(float), stream);

  // input splits (channel-padded)
  split_pad_k<<<9600, 256, 0, stream>>>(mel_x, (__bf16*)(wsb + MXH), (__bf16*)(wsb + MXL), 80, 96, 2457600L);
  split_pad_k<<<12800, 256, 0, stream>>>(txt_x, (__bf16*)(wsb + TXH), (__bf16*)(wsb + TXL), 512, 512, 3276800L);
  // weight repack+split
  wsplit_k<<<2880, 256, 0, stream>>>(mel_w1, (__bf16*)(wsb + W1MH), (__bf16*)(wsb + W1ML), 80, 5, 96, 737280L);
  wsplit_k<<<5760, 256, 0, stream>>>(mel_w2, (__bf16*)(wsb + W2MH), (__bf16*)(wsb + W2ML), 768, 5, 768, 1474560L);
  wsplit_k<<<9216, 256, 0, stream>>>(txt_w1, (__bf16*)(wsb + W1TH), (__bf16*)(wsb + W1TL), 512, 3, 512, 2359296L);
  wsplit_k<<<3456, 256, 0, stream>>>(txt_w2, (__bf16*)(wsb + W2TH), (__bf16*)(wsb + W2TL), 768, 3, 768, 884736L);
  wsplit_k<<<576, 256, 0, stream>>>(wq, (__bf16*)(wsb + WQH), (__bf16*)(wsb + WQL), 384, 1, 384, 147456L);
  wsplit_k<<<576, 256, 0, stream>>>(wk, (__bf16*)(wsb + WKH), (__bf16*)(wsb + WKL), 384, 1, 384, 147456L);

  // text pipeline (conv1 -> conv2 overwrites dead TXH/TXL region)
  conv1_mfma<512, 3, 400><<<dim3(4, 12, B), 256, 0, stream>>>(
      (const __bf16*)(wsb + TXH), (const __bf16*)(wsb + TXL),
      (const __bf16*)(wsb + W1TH), (const __bf16*)(wsb + W1TL),
      txt_b1, xl, (__bf16*)(wsb + HH), (__bf16*)(wsb + HL));
  conv2_mfma<768, 3, 400, true, true, false><<<dim3(4, 3, B), 256, 0, stream>>>(
      (const __bf16*)(wsb + HH), (const __bf16*)(wsb + HL),
      (const __bf16*)(wsb + W2TH), (const __bf16*)(wsb + W2TL),
      txt_b2, xl, nullptr, (__bf16*)(wsb + TPH), (__bf16*)(wsb + TPL));

  // mel pipeline
  conv1_mfma<96, 5, 1600><<<dim3(13, 12, B), 256, 0, stream>>>(
      (const __bf16*)(wsb + MXH), (const __bf16*)(wsb + MXL),
      (const __bf16*)(wsb + W1MH), (const __bf16*)(wsb + W1ML),
      mel_b1, yl, (__bf16*)(wsb + HH), (__bf16*)(wsb + HL));
  conv2_mfma<768, 5, 1600, true, true, false><<<dim3(13, 3, B), 256, 0, stream>>>(
      (const __bf16*)(wsb + HH), (const __bf16*)(wsb + HL),
      (const __bf16*)(wsb + W2MH), (const __bf16*)(wsb + W2ML),
      mel_b2, yl, nullptr, (__bf16*)(wsb + PH), (__bf16*)(wsb + PL));

  // q/k projections (MFMA, K=1) — H region now dead, holds q / kT
  conv2_mfma<384, 1, 400, false, false, true><<<dim3(4, 3, B), 256, 0, stream>>>(
      (const __bf16*)(wsb + TPH), (const __bf16*)(wsb + TPL),
      (const __bf16*)(wsb + WKH), (const __bf16*)(wsb + WKL),
      bk, xl, (float*)(wsb + KTB), nullptr, nullptr);
  conv2_mfma<384, 1, 1600, false, false, false><<<dim3(13, 3, B), 256, 0, stream>>>(
      (const __bf16*)(wsb + PH), (const __bf16*)(wsb + PL),
      (const __bf16*)(wsb + WQH), (const __bf16*)(wsb + WQL),
      bq, yl, (float*)(wsb + QB), nullptr, nullptr);

  // attention + MAS
  scores_k<<<dim3(100, B), 512, 0, stream>>>(
      (const float*)(wsb + QB), (const float*)(wsb + KTB), xl, yl, o_attn, o_logp);
  mas_fwd<<<B, 64, 0, stream>>>(o_logp, xl, yl, (unsigned char*)(wsb + BITS));
  mas_bt<<<B, 64, 0, stream>>>((const unsigned char*)(wsb + BITS), xl, yl, o_hard, o_dur);
}

// Round 7
// 1638.625 us; speedup vs baseline: 1.1569x; 1.0852x over previous
//
#include <hip/hip_runtime.h>
#include <cstdint>

#define B 16
#define TY 1600
#define TX 400
#define MAS 384
#define HID 768
#define NEGV -1e9f

typedef __bf16 bf16x8 __attribute__((ext_vector_type(8)));
typedef float  f32x4  __attribute__((ext_vector_type(4)));

__device__ __forceinline__ f32x4 mfma16(bf16x8 a, bf16x8 b, f32x4 c) {
  return __builtin_amdgcn_mfma_f32_16x16x32_bf16(a, b, c, 0, 0, 0);
}

// ---------------- fp32 -> bf16 hi/lo split with channel padding ----------------
__global__ void split_pad_k(const float* __restrict__ in, __bf16* __restrict__ oh,
                            __bf16* __restrict__ ol, int CIN, int CINP, long n) {
  long i = (long)blockIdx.x * 256 + threadIdx.x;
  if (i >= n) return;
  long row = i / CINP; int ci = (int)(i - row * CINP);
  float v = (ci < CIN) ? in[row * CIN + ci] : 0.f;
  __bf16 h = (__bf16)v;
  oh[i] = h; ol[i] = (__bf16)(v - (float)h);
}

// ---------------- weight repack+split: w[N][CIN][K] -> oh/ol[N][k*CINP + ci] ----------------
__global__ void wsplit_k(const float* __restrict__ w, __bf16* __restrict__ oh,
                         __bf16* __restrict__ ol, int CIN, int K_, int CINP, long n) {
  long i = (long)blockIdx.x * 256 + threadIdx.x;
  if (i >= n) return;
  long kdspan = (long)K_ * CINP;
  long nn = i / kdspan; int kd = (int)(i - nn * kdspan);
  int k = kd / CINP, ci = kd - k * CINP;
  float v = (ci < CIN) ? w[(nn * CIN + ci) * K_ + k] : 0.f;
  __bf16 h = (__bf16)v;
  oh[i] = h; ol[i] = (__bf16)(v - (float)h);
}

// ---------------- conv1 + ReGLU, split-bf16 MFMA (unchanged, grid already large) ----------------
template<int CINP, int K, int T>
__global__ __launch_bounds__(256)
void conv1_mfma(const __bf16* __restrict__ xh, const __bf16* __restrict__ xl,
                const __bf16* __restrict__ wh, const __bf16* __restrict__ wl,
                const float* __restrict__ bias, const int* __restrict__ lens,
                __bf16* __restrict__ hh, __bf16* __restrict__ hl)
{
  constexpr int BM = 128, PAD = K / 2, ROWS = BM + K - 1, KD = K * CINP;
  __shared__ float4 xs[8 * ROWS];
  const int b = blockIdx.z, t0 = blockIdx.x * BM, n0 = blockIdx.y * 64;
  const int tid = threadIdx.x, wid = tid >> 6, lane = tid & 63;
  const int wm = wid >> 1, wn = wid & 1, lr = lane & 15, lg = lane >> 4;
  const int len = lens[b];
  const f32x4 Z4 = {0.f, 0.f, 0.f, 0.f};
  f32x4 acc_a[4][2], acc_g[4][2];
  #pragma unroll
  for (int m = 0; m < 4; ++m)
    #pragma unroll
    for (int n = 0; n < 2; ++n) { acc_a[m][n] = Z4; acc_g[m][n] = Z4; }

  #pragma unroll 1
  for (int ci0 = 0; ci0 < CINP; ci0 += 32) {
    __syncthreads();
    for (int e = tid; e < ROWS * 8; e += 256) {
      int row = e >> 3, sc = e & 7, spl = sc >> 2, cg = sc & 3;
      int t = t0 + row - PAD;
      float4 v = {0.f, 0.f, 0.f, 0.f};
      if (t >= 0 && t < len)
        v = *(const float4*)((spl ? xl : xh) + ((size_t)b * T + t) * CINP + ci0 + cg * 8);
      xs[(spl * 4 + cg) * ROWS + row] = v;
    }
    __syncthreads();
    #pragma unroll
    for (int k = 0; k < K; ++k) {
      bf16x8 ah[4], al[4];
      #pragma unroll
      for (int mf = 0; mf < 4; ++mf) {
        int row = wm * 64 + mf * 16 + lr + k;
        ah[mf] = *(const bf16x8*)&xs[lg * ROWS + row];
        al[mf] = *(const bf16x8*)&xs[(4 + lg) * ROWS + row];
      }
      size_t kd = (size_t)k * CINP + ci0 + lg * 8;
      #pragma unroll
      for (int nf = 0; nf < 2; ++nf) {
        int na = n0 + wn * 32 + nf * 16 + lr;
        bf16x8 bah = *(const bf16x8*)(wh + (size_t)na * KD + kd);
        bf16x8 bal = *(const bf16x8*)(wl + (size_t)na * KD + kd);
        bf16x8 bgh = *(const bf16x8*)(wh + (size_t)(na + HID) * KD + kd);
        bf16x8 bgl = *(const bf16x8*)(wl + (size_t)(na + HID) * KD + kd);
        #pragma unroll
        for (int mf = 0; mf < 4; ++mf) {
          acc_a[mf][nf] = mfma16(ah[mf], bah, acc_a[mf][nf]);
          acc_a[mf][nf] = mfma16(ah[mf], bal, acc_a[mf][nf]);
          acc_a[mf][nf] = mfma16(al[mf], bah, acc_a[mf][nf]);
          acc_g[mf][nf] = mfma16(ah[mf], bgh, acc_g[mf][nf]);
          acc_g[mf][nf] = mfma16(ah[mf], bgl, acc_g[mf][nf]);
          acc_g[mf][nf] = mfma16(al[mf], bgh, acc_g[mf][nf]);
        }
      }
    }
  }
  #pragma unroll
  for (int nf = 0; nf < 2; ++nf) {
    int c = n0 + wn * 32 + nf * 16 + lr;
    float ba = bias[c], bg = bias[c + HID];
    #pragma unroll
    for (int mf = 0; mf < 4; ++mf) {
      #pragma unroll
      for (int r = 0; r < 4; ++r) {
        int t = t0 + wm * 64 + mf * 16 + lg * 4 + r;
        if (t < T) {
          float a = acc_a[mf][nf][r] + ba;
          float g = acc_g[mf][nf][r] + bg;
          float v = a * fmaxf(g, 0.f);
          __bf16 vh = (__bf16)v;
          size_t o = ((size_t)b * T + t) * HID + c;
          hh[o] = vh;
          hl[o] = (__bf16)(v - (float)vh);
        }
      }
    }
  }
}

// ---------------- conv2 / linear, split-bf16 MFMA ----------------
// BM=64, 4 waves as 1x4 (each wave: 64 rows x 32 cols) -> 1200 blocks for T=1600.
// A-tile stride padded +1 float4: lg-groups land on banks {0,20,8,28} (2-way max).
template<int CINP, int K, int T, bool MASK, bool SPLITOUT, bool STORET>
__global__ __launch_bounds__(256)
void conv2_mfma(const __bf16* __restrict__ xh, const __bf16* __restrict__ xl,
                const __bf16* __restrict__ wh, const __bf16* __restrict__ wl,
                const float* __restrict__ bias, const int* __restrict__ lens,
                float* __restrict__ out, __bf16* __restrict__ oh, __bf16* __restrict__ ol)
{
  constexpr int BM = 64, PAD = K / 2, ROWS = BM + K - 1, STRIDE = ROWS + 1, KD = K * CINP;
  __shared__ float4 xs[8 * STRIDE];
  const int b = blockIdx.z, t0 = blockIdx.x * BM, n0 = blockIdx.y * 128;
  const int tid = threadIdx.x, wn = tid >> 6, lane = tid & 63;
  const int lr = lane & 15, lg = lane >> 4;
  const int len = lens[b];
  const f32x4 Z4 = {0.f, 0.f, 0.f, 0.f};
  f32x4 acc[4][2];
  #pragma unroll
  for (int m = 0; m < 4; ++m)
    #pragma unroll
    for (int n = 0; n < 2; ++n) acc[m][n] = Z4;

  #pragma unroll 1
  for (int ci0 = 0; ci0 < CINP; ci0 += 32) {
    __syncthreads();
    for (int e = tid; e < ROWS * 8; e += 256) {
      int row = e >> 3, sc = e & 7, spl = sc >> 2, cg = sc & 3;
      int t = t0 + row - PAD;
      float4 v = {0.f, 0.f, 0.f, 0.f};
      if (t >= 0 && t < len)
        v = *(const float4*)((spl ? xl : xh) + ((size_t)b * T + t) * CINP + ci0 + cg * 8);
      xs[(spl * 4 + cg) * STRIDE + row] = v;
    }
    __syncthreads();
    #pragma unroll
    for (int k = 0; k < K; ++k) {
      bf16x8 ah[4], al[4];
      #pragma unroll
      for (int mf = 0; mf < 4; ++mf) {
        int row = mf * 16 + lr + k;
        ah[mf] = *(const bf16x8*)&xs[lg * STRIDE + row];
        al[mf] = *(const bf16x8*)&xs[(4 + lg) * STRIDE + row];
      }
      size_t kd = (size_t)k * CINP + ci0 + lg * 8;
      #pragma unroll
      for (int nf = 0; nf < 2; ++nf) {
        int nc = n0 + wn * 32 + nf * 16 + lr;
        bf16x8 bh = *(const bf16x8*)(wh + (size_t)nc * KD + kd);
        bf16x8 bl = *(const bf16x8*)(wl + (size_t)nc * KD + kd);
        #pragma unroll
        for (int mf = 0; mf < 4; ++mf) {
          acc[mf][nf] = mfma16(ah[mf], bh, acc[mf][nf]);
          acc[mf][nf] = mfma16(ah[mf], bl, acc[mf][nf]);
          acc[mf][nf] = mfma16(al[mf], bh, acc[mf][nf]);
        }
      }
    }
  }
  #pragma unroll
  for (int nf = 0; nf < 2; ++nf) {
    int c = n0 + wn * 32 + nf * 16 + lr;
    float bb = bias[c];
    #pragma unroll
    for (int mf = 0; mf < 4; ++mf) {
      #pragma unroll
      for (int r = 0; r < 4; ++r) {
        int t = t0 + mf * 16 + lg * 4 + r;
        if (t < T) {
          float v = acc[mf][nf][r] + bb;
          if (MASK && t >= len) v = 0.f;
          if (SPLITOUT) {
            __bf16 vh = (__bf16)v;
            size_t o = ((size_t)b * T + t) * MAS + c;
            oh[o] = vh;
            ol[o] = (__bf16)(v - (float)vh);
          } else if (STORET) {
            out[((size_t)b * MAS + c) * T + t] = v;
          } else {
            out[((size_t)b * T + t) * MAS + c] = v;
          }
        }
      }
    }
  }
}

// ---------------- scores + softmax + safe_log ----------------
__global__ __launch_bounds__(512)
void scores_k(const float* __restrict__ q, const float* __restrict__ kT,
              const int* __restrict__ xl, const int* __restrict__ yl,
              float* __restrict__ oattn, float* __restrict__ ologp)
{
  __shared__ float qs[16 * 384];
  __shared__ float tmp[8];
  const int b = blockIdx.y, y0 = blockIdx.x * 16, tid = threadIdx.x;
  for (int e = tid; e < 16 * 384; e += 512)
    qs[e] = q[((size_t)b * TY + (y0 + e / 384)) * 384 + (e - (e / 384) * 384)];
  __syncthreads();
  float acc[16];
  #pragma unroll
  for (int i = 0; i < 16; ++i) acc[i] = 0.f;
  const int x = tid;
  if (x < TX) {
    const float* kb = kT + (size_t)b * MAS * TX + x;
    for (int d = 0; d < 384; d += 4) {
      float k0 = kb[(size_t)(d + 0) * TX], k1 = kb[(size_t)(d + 1) * TX];
      float k2 = kb[(size_t)(d + 2) * TX], k3 = kb[(size_t)(d + 3) * TX];
      #pragma unroll
      for (int yy = 0; yy < 16; ++yy) {
        float4 qv = *(const float4*)&qs[yy * 384 + d];
        acc[yy] = fmaf(qv.x, k0, fmaf(qv.y, k1, fmaf(qv.z, k2, fmaf(qv.w, k3, acc[yy]))));
      }
    }
  }
  const int xlen = xl[b], ylen = yl[b];
  const float scale = 0.05103103630798288f;
  const bool xpad = (x >= xlen);
  const int wv = tid >> 6, ln = tid & 63;
  #pragma unroll 1
  for (int yy = 0; yy < 16; ++yy) {
    int y = y0 + yy;
    float s = -3.0e38f;
    if (x < TX) {
      s = acc[yy] * scale;
      if (xpad && (y >= ylen)) s = -1e-9f;
    }
    float m = s;
    for (int off = 32; off; off >>= 1) m = fmaxf(m, __shfl_xor(m, off));
    if (ln == 0) tmp[wv] = m;
    __syncthreads();
    float mx = fmaxf(fmaxf(fmaxf(tmp[0], tmp[1]), fmaxf(tmp[2], tmp[3])),
                     fmaxf(fmaxf(tmp[4], tmp[5]), fmaxf(tmp[6], tmp[7])));
    __syncthreads();
    float e = (x < TX) ? expf(s - mx) : 0.f;
    float sm = e;
    for (int off = 32; off; off >>= 1) sm += __shfl_xor(sm, off);
    if (ln == 0) tmp[wv] = sm;
    __syncthreads();
    float tot = tmp[0] + tmp[1] + tmp[2] + tmp[3] + tmp[4] + tmp[5] + tmp[6] + tmp[7];
    __syncthreads();
    if (x < TX) {
      float w = e / tot;
      size_t o = ((size_t)b * TY + y) * TX + x;
      oattn[o] = w;
      ologp[o] = logf(w + 1e-6f);
    }
  }
}

// ---------------- MAS forward: 4-row blocked DP, halo windows, no per-row shfl ----------------
#define MAS_LD(blkv, buf) do {                                           \
    int base_ = (blkv) * 4;                                              \
    _Pragma("unroll")                                                    \
    for (int d_ = 0; d_ < 4; ++d_) {                                     \
      int yr_ = base_ + d_; if (yr_ > TY - 1) yr_ = TY - 1;              \
      const float* r_ = lpb + (size_t)yr_ * TX;                          \
      buf[d_ * 3 + 0] = *(const float4*)(r_ + lb0);                      \
      buf[d_ * 3 + 1] = *(const float4*)(r_ + lb1);                      \
      buf[d_ * 3 + 2] = *(const float4*)(r_ + lb2);                      \
    } } while (0)

#define MAS_BLK(blkv, buf) do {                                          \
    float h0 = __shfl_up(w[8], 1),  h1 = __shfl_up(w[9], 1);             \
    float h2 = __shfl_up(w[10], 1), h3 = __shfl_up(w[11], 1);            \
    w[0] = lane ? h0 : NEGV; w[1] = lane ? h1 : NEGV;                    \
    w[2] = lane ? h2 : NEGV; w[3] = lane ? h3 : NEGV;                    \
    const int y0_ = (blkv) * 4;                                          \
    const bool ph1_ = (y0_ < TX);                                        \
    _Pragma("unroll")                                                    \
    for (int d_ = 0; d_ < 4; ++d_) {                                     \
      const int y_ = y0_ + d_;                                           \
      float lp[12];                                                      \
      _Pragma("unroll")                                                  \
      for (int k_ = 0; k_ < 3; ++k_) {                                   \
        float4 v_ = buf[d_ * 3 + k_];                                    \
        lp[k_*4+0] = v_.x + wxm[k_*4+0]; lp[k_*4+1] = v_.y + wxm[k_*4+1];\
        lp[k_*4+2] = v_.z + wxm[k_*4+2]; lp[k_*4+3] = v_.w + wxm[k_*4+3];\
      }                                                                  \
      if (ph1_) {                                                        \
        int c_ = y_ - p0;                                                \
        _Pragma("unroll")                                                \
        for (int i_ = 0; i_ < 12; ++i_) lp[i_] = (i_ <= c_) ? lp[i_] : NEGV; \
      }                                                                  \
      unsigned byte_ = 0;                                                \
      _Pragma("unroll")                                                  \
      for (int j_ = 0; j_ < 8; ++j_)                                     \
        byte_ |= (w[j_ + 3] > w[j_ + 4]) ? (1u << j_) : 0u;              \
      float nw[12];                                                      \
      nw[0] = lp[0] + w[0];                                              \
      _Pragma("unroll")                                                  \
      for (int i_ = 1; i_ < 12; ++i_) nw[i_] = lp[i_] + fmaxf(w[i_], w[i_ - 1]); \
      bb[(size_t)y_ * 64 + lane] = (unsigned char)byte_;                 \
      _Pragma("unroll")                                                  \
      for (int i_ = 0; i_ < 12; ++i_) w[i_] = nw[i_];                    \
    } } while (0)

__global__ __launch_bounds__(64)
void mas_fwd(const float* __restrict__ logprob, const int* __restrict__ xl,
             const int* __restrict__ yl, unsigned char* __restrict__ bits)
{
  const int b = blockIdx.x;
  const int lane = threadIdx.x;
  const int xlen = xl[b], ylen = yl[b];
  const float* lpb = logprob + (size_t)b * TY * TX;
  unsigned char* bb = bits + (size_t)b * TY * 64;
  const int p0 = lane * 8 - 4;
  int t;
  t = p0;     if (t < 0) t = 0; if (t > 396) t = 396; const int lb0 = t;
  t = p0 + 4; if (t < 0) t = 0; if (t > 396) t = 396; const int lb1 = t;
  t = p0 + 8; if (t < 0) t = 0; if (t > 396) t = 396; const int lb2 = t;

  float w[12], wxm[12];
  #pragma unroll
  for (int i = 0; i < 12; ++i) {
    int p = p0 + i;
    wxm[i] = (p >= 0 && p < xlen) ? 0.f : NEGV;
    w[i] = (p == 0) ? 0.f : NEGV;
  }

  float4 bufA[12], bufB[12];
  MAS_LD(0, bufA);
  MAS_LD(1, bufB);
  const int nblk = (ylen + 3) >> 2;
  int blk = 0;
  #pragma unroll 1
  for (; blk + 1 < nblk; blk += 2) {
    MAS_BLK(blk, bufA);
    MAS_LD(blk + 2, bufA);
    MAS_BLK(blk + 1, bufB);
    MAS_LD(blk + 3, bufB);
  }
  if (blk < nblk) MAS_BLK(blk, bufA);
}

// ---------------- MAS backtrack: uniform scalar walk via readlane, run-painted output ----------------
__global__ __launch_bounds__(64)
void mas_bt(const unsigned char* __restrict__ bits, const int* __restrict__ xl,
            const int* __restrict__ yl, float* __restrict__ hard, float* __restrict__ dur)
{
  const int b = blockIdx.x;
  const int lane = threadIdx.x;
  const int xlen = xl[b], ylen = yl[b];
  const unsigned char* bb = bits + (size_t)b * TY * 64;
  float* hb = hard + (size_t)b * TX * TY;
  float* db = dur + (size_t)b * TX;

  int x = xlen - 1;
  int cnt = 0;
  #pragma unroll 1
  for (int ycur = ylen - 1; ycur >= 0; ycur -= 64) {
    int lo = x - 63; if (lo < 0) lo = 0;
    const int wb = (lo >> 3) & ~3;
    int ry = ycur - lane;
    unsigned w0 = 0, w1 = 0, w2 = 0;
    if (ry >= 0) {
      const unsigned* rp = (const unsigned*)(bb + (size_t)ry * 64 + wb);
      w0 = rp[0]; w1 = rp[1]; w2 = rp[2];
    }
    const int rows = (ycur + 1 < 64) ? (ycur + 1) : 64;
    #pragma unroll 1
    for (int s = 0; s < rows; s += 8) {
      const int cnt8 = (rows - s < 8) ? (rows - s) : 8;
      unsigned r0[8], r1[8], r2[8];
      #pragma unroll
      for (int u = 0; u < 8; ++u) {
        r0[u] = (unsigned)__builtin_amdgcn_readlane((int)w0, s + u);
        r1[u] = (unsigned)__builtin_amdgcn_readlane((int)w1, s + u);
        r2[u] = (unsigned)__builtin_amdgcn_readlane((int)w2, s + u);
      }
      #pragma unroll
      for (int u = 0; u < 8; ++u) {
        if (u < cnt8) {
          const int yy = ycur - s - u;
          ++cnt;
          if (yy > 0 && x > 0) {
            const int boff = (x >> 3) - wb;
            const unsigned word = (boff < 4) ? r0[u] : ((boff < 8) ? r1[u] : r2[u]);
            const unsigned byte = word >> ((boff & 3) * 8);
            if ((x == yy) || ((byte >> (x & 7)) & 1)) {
              for (int q = lane; q < cnt; q += 64) hb[(size_t)x * TY + yy + q] = 1.0f;
              if (lane == 0) db[x] = (float)cnt;
              cnt = 0;
              --x;
            }
          }
        }
      }
    }
  }
  for (int q = lane; q < cnt; q += 64) hb[(size_t)x * TY + q] = 1.0f;
  if (lane == 0) db[x] = (float)cnt;
}

extern "C" void kernel_launch(void* const* d_in, const int* in_sizes, int n_in,
                              void* d_out, int out_size, void* d_ws, size_t ws_size,
                              hipStream_t stream) {
  const float* mel_x  = (const float*)d_in[0];
  const float* txt_x  = (const float*)d_in[1];
  const float* mel_w1 = (const float*)d_in[2];
  const float* mel_b1 = (const float*)d_in[3];
  const float* mel_w2 = (const float*)d_in[4];
  const float* mel_b2 = (const float*)d_in[5];
  const float* txt_w1 = (const float*)d_in[6];
  const float* txt_b1 = (const float*)d_in[7];
  const float* txt_w2 = (const float*)d_in[8];
  const float* txt_b2 = (const float*)d_in[9];
  const float* wq     = (const float*)d_in[10];
  const float* bq     = (const float*)d_in[11];
  const float* wk     = (const float*)d_in[12];
  const float* bk     = (const float*)d_in[13];
  const int*   xl     = (const int*)d_in[14];
  const int*   yl     = (const int*)d_in[15];

  char* wsb = (char*)d_ws;
  constexpr size_t MXH  = 0;
  constexpr size_t MXL  = MXH  + 4915200;
  constexpr size_t TXH  = MXL  + 4915200;
  constexpr size_t TXL  = TXH  + 6553600;
  constexpr size_t TPH  = TXH;
  constexpr size_t TPL  = TXH  + 4915200;
  constexpr size_t W1MH = TXL  + 6553600;
  constexpr size_t W1ML = W1MH + 1474560;
  constexpr size_t W2MH = W1ML + 1474560;
  constexpr size_t W2ML = W2MH + 2949120;
  constexpr size_t W1TH = W2ML + 2949120;
  constexpr size_t W1TL = W1TH + 4718592;
  constexpr size_t W2TH = W1TL + 4718592;
  constexpr size_t W2TL = W2TH + 1769472;
  constexpr size_t WQH  = W2TL + 1769472;
  constexpr size_t WQL  = WQH  + 294912;
  constexpr size_t WKH  = WQL  + 294912;
  constexpr size_t WKL  = WKH  + 294912;
  constexpr size_t HH   = WKL  + 294912;
  constexpr size_t HL   = HH   + 39321600;
  constexpr size_t QB   = HH;
  constexpr size_t KTB  = HL;
  constexpr size_t BITS = HL   + 10240000;
  constexpr size_t PH   = HL   + 39321600;
  constexpr size_t PL   = PH   + 19660800;

  float* out = (float*)d_out;
  float* o_attn = out;
  float* o_logp = out + (size_t)10240000;
  float* o_hard = out + (size_t)20480000;
  float* o_dur  = out + (size_t)30720000;

  hipMemsetAsync(o_hard, 0, (size_t)(10240000 + 6400) * sizeof(float), stream);

  split_pad_k<<<9600, 256, 0, stream>>>(mel_x, (__bf16*)(wsb + MXH), (__bf16*)(wsb + MXL), 80, 96, 2457600L);
  split_pad_k<<<12800, 256, 0, stream>>>(txt_x, (__bf16*)(wsb + TXH), (__bf16*)(wsb + TXL), 512, 512, 3276800L);
  wsplit_k<<<2880, 256, 0, stream>>>(mel_w1, (__bf16*)(wsb + W1MH), (__bf16*)(wsb + W1ML), 80, 5, 96, 737280L);
  wsplit_k<<<5760, 256, 0, stream>>>(mel_w2, (__bf16*)(wsb + W2MH), (__bf16*)(wsb + W2ML), 768, 5, 768, 1474560L);
  wsplit_k<<<9216, 256, 0, stream>>>(txt_w1, (__bf16*)(wsb + W1TH), (__bf16*)(wsb + W1TL), 512, 3, 512, 2359296L);
  wsplit_k<<<3456, 256, 0, stream>>>(txt_w2, (__bf16*)(wsb + W2TH), (__bf16*)(wsb + W2TL), 768, 3, 768, 884736L);
  wsplit_k<<<576, 256, 0, stream>>>(wq, (__bf16*)(wsb + WQH), (__bf16*)(wsb + WQL), 384, 1, 384, 147456L);
  wsplit_k<<<576, 256, 0, stream>>>(wk, (__bf16*)(wsb + WKH), (__bf16*)(wsb + WKL), 384, 1, 384, 147456L);

  // text pipeline
  conv1_mfma<512, 3, 400><<<dim3(4, 12, B), 256, 0, stream>>>(
      (const __bf16*)(wsb + TXH), (const __bf16*)(wsb + TXL),
      (const __bf16*)(wsb + W1TH), (const __bf16*)(wsb + W1TL),
      txt_b1, xl, (__bf16*)(wsb + HH), (__bf16*)(wsb + HL));
  conv2_mfma<768, 3, 400, true, true, false><<<dim3(7, 3, B), 256, 0, stream>>>(
      (const __bf16*)(wsb + HH), (const __bf16*)(wsb + HL),
      (const __bf16*)(wsb + W2TH), (const __bf16*)(wsb + W2TL),
      txt_b2, xl, nullptr, (__bf16*)(wsb + TPH), (__bf16*)(wsb + TPL));

  // mel pipeline
  conv1_mfma<96, 5, 1600><<<dim3(13, 12, B), 256, 0, stream>>>(
      (const __bf16*)(wsb + MXH), (const __bf16*)(wsb + MXL),
      (const __bf16*)(wsb + W1MH), (const __bf16*)(wsb + W1ML),
      mel_b1, yl, (__bf16*)(wsb + HH), (__bf16*)(wsb + HL));
  conv2_mfma<768, 5, 1600, true, true, false><<<dim3(25, 3, B), 256, 0, stream>>>(
      (const __bf16*)(wsb + HH), (const __bf16*)(wsb + HL),
      (const __bf16*)(wsb + W2MH), (const __bf16*)(wsb + W2ML),
      mel_b2, yl, nullptr, (__bf16*)(wsb + PH), (__bf16*)(wsb + PL));

  // q/k projections (MFMA, K=1)
  conv2_mfma<384, 1, 400, false, false, true><<<dim3(7, 3, B), 256, 0, stream>>>(
      (const __bf16*)(wsb + TPH), (const __bf16*)(wsb + TPL),
      (const __bf16*)(wsb + WKH), (const __bf16*)(wsb + WKL),
      bk, xl, (float*)(wsb + KTB), nullptr, nullptr);
  conv2_mfma<384, 1, 1600, false, false, false><<<dim3(25, 3, B), 256, 0, stream>>>(
      (const __bf16*)(wsb + PH), (const __bf16*)(wsb + PL),
      (const __bf16*)(wsb + WQH), (const __bf16*)(wsb + WQL),
      bq, yl, (float*)(wsb + QB), nullptr, nullptr);

  // attention + MAS
  scores_k<<<dim3(100, B), 512, 0, stream>>>(
      (const float*)(wsb + QB), (const float*)(wsb + KTB), xl, yl, o_attn, o_logp);
  mas_fwd<<<B, 64, 0, stream>>>(o_logp, xl, yl, (unsigned char*)(wsb + BITS));
  mas_bt<<<B, 64, 0, stream>>>((const unsigned char*)(wsb + BITS), xl, yl, o_hard, o_dur);
}